// Round 14
// baseline (904.360 us; speedup 1.0000x reference)
//
#include <hip/hip_runtime.h>
#include <math.h>

#define NB 128      // B
#define NT 12       // T
#define NNODE 207   // N
#define NF 14       // F
#define NH 128      // H
#define ROWS (NB*NNODE)      // 26496
#define BTN (NB*NT*NNODE)    // 317952
#define G3 (3*NH)            // 384
#define LSTR 208             // padded Laplacian row stride
#define RG (ROWS/16)         // 1656 row-groups of 16

typedef __attribute__((ext_vector_type(8))) short short8;   // 8 bf16 = 4 VGPR
typedef __attribute__((ext_vector_type(4))) float accf4;    // MFMA C/D

#define MFMA16 __builtin_amdgcn_mfma_f32_16x16x32_bf16

__device__ __forceinline__ float sigf(float x){ return 1.0f/(1.0f+__expf(-x)); }
__device__ __forceinline__ float tanhfast(float x){
  float e = __expf(2.f*x);
  return 1.f - 2.f/(e + 1.f);
}
__device__ __forceinline__ unsigned short f2b(float f){
  unsigned int u = __float_as_uint(f);
  return (unsigned short)((u + 0x7FFFu + ((u>>16)&1u)) >> 16);
}
__device__ __forceinline__ float b2f(unsigned short h){
  return __uint_as_float(((unsigned int)h) << 16);
}
// split-bf16 3-term product: hi*hi + lo*hi + hi*lo (lo*lo ~2^-16, negligible)
__device__ __forceinline__ void mm3(short8 ah, short8 al, short8 bh, short8 bl, accf4& acc){
  acc = MFMA16(ah, bh, acc, 0,0,0);
  acc = MFMA16(al, bh, acc, 0,0,0);
  acc = MFMA16(ah, bl, acc, 0,0,0);
}

__global__ __launch_bounds__(256) void k_sentinel(float* __restrict__ out, int n){
  int i = blockIdx.x*256 + threadIdx.x;
  if (i < n) out[i] = 12345.0f;
}

// ---- weight prep (fragment-layout bf16 hi/lo) ----
#define NW_ENC (7*24*64*8)   // 86016
#define NW_DEC (4*24*64*8)   // 49152
#define SH_TOTAL (2*NW_ENC + 2*NW_DEC)
#define FWT_TOTAL (32*384 + 384)
#define PREP_TOTAL (NW_ENC + NW_DEC + 32*384 + 384)
__global__ __launch_bounds__(256) void k_prep(const float* __restrict__ ewih,
    const float* __restrict__ ewhh, const float* __restrict__ dwih,
    const float* __restrict__ dwhh, short* __restrict__ ws, float* __restrict__ wf){
  int i = blockIdx.x*256 + threadIdx.x;
  if (i < NW_ENC){
    int e = i & 7, lane = (i>>3) & 63, ct = (i>>9) % 24, ks = i / 12288;
    int k = ks*32 + (lane>>4)*8 + e;
    int col = ct*16 + (lane&15);
    float wv = (k < 65) ? ewih[col*65 + k] : ((k < 96) ? 0.f : ewhh[col*128 + (k-96)]);
    unsigned short hi = f2b(wv);
    ws[i] = (short)hi;
    ws[NW_ENC + i] = (short)f2b(wv - b2f(hi));
  } else if (i < NW_ENC + NW_DEC){
    int j = i - NW_ENC;
    int e = j & 7, lane = (j>>3) & 63, ct = (j>>9) % 24, ks = j / 12288;
    int k = ks*32 + (lane>>4)*8 + e;
    int col = ct*16 + (lane&15);
    float wv = dwhh[col*128 + k];
    unsigned short hi = f2b(wv);
    ws[2*NW_ENC + j] = (short)hi;
    ws[2*NW_ENC + NW_DEC + j] = (short)f2b(wv - b2f(hi));
  } else if (i < NW_ENC + NW_DEC + 32*384){
    int j = i - (NW_ENC + NW_DEC); int k = j/384, n = j%384;
    wf[j] = dwih[n*33 + 1 + k];
  } else if (i < PREP_TOTAL){
    int n = i - (NW_ENC + NW_DEC + 32*384);
    wf[32*384 + n] = dwih[n*33];
  }
}

// emb = tanh(state * fc_w + fc_b)
__global__ __launch_bounds__(256) void k_emb(const float* __restrict__ x,
    const float* __restrict__ w, const float* __restrict__ b, float* __restrict__ emb){
  int idx = blockIdx.x*256 + threadIdx.x;
  if (idx >= ROWS*16) return;
  int j = idx & 15, row = idx >> 4;
  int bb = row / NNODE, n = row % NNODE;
  float s = x[((bb*NT + (NT-1))*NNODE + n)*NF];
  emb[idx] = tanhf(s*w[j] + b[j]);
}

// wave-per-row adjacency
__global__ __launch_bounds__(256) void k_adj(const float* __restrict__ emb,
    const float* __restrict__ Aph, const float* __restrict__ alp,
    float* __restrict__ Abuf, float* __restrict__ rsum){
  int wid = threadIdx.x >> 6, lane = threadIdx.x & 63;
  int row = blockIdx.x*4 + wid;
  int bb = row / NNODE, n = row % NNODE;
  const float4* er = (const float4*)(emb + (size_t)row*16);
  float4 e0 = er[0], e1 = er[1], e2 = er[2], e3 = er[3];
  float d[4];
  #pragma unroll
  for (int q=0;q<4;++q){
    int m = lane + q*64;
    float dd = -1.f;
    if (m < NNODE){
      const float4* em = (const float4*)(emb + (size_t)(bb*NNODE+m)*16);
      float4 m0 = em[0], m1 = em[1], m2 = em[2], m3 = em[3];
      dd = e0.x*m0.x + e0.y*m0.y + e0.z*m0.z + e0.w*m0.w
         + e1.x*m1.x + e1.y*m1.y + e1.z*m1.z + e1.w*m1.w
         + e2.x*m2.x + e2.y*m2.y + e2.z*m2.z + e2.w*m2.w
         + e3.x*m3.x + e3.y*m3.y + e3.z*m3.z + e3.w*m3.w;
      dd = dd > 0.f ? dd : 0.f;
    }
    d[q] = dd;
  }
  int km = 0;
  float vmax = 0.f;
  for (int it=0; it<10; ++it){
    float v = -1.f; int mi = 1<<20;
    #pragma unroll
    for (int q=0;q<4;++q){
      if (d[q] >= 0.f && !((km>>q)&1) && d[q] > v){ v = d[q]; mi = lane + q*64; }
    }
    #pragma unroll
    for (int off=1; off<64; off<<=1){
      float v2 = __shfl_xor(v, off, 64);
      int  i2 = __shfl_xor(mi, off, 64);
      if (v2 > v || (v2 == v && i2 < mi)){ v = v2; mi = i2; }
    }
    if (it == 0) vmax = v;
    if ((mi & 63) == lane) km |= 1 << (mi >> 6);
  }
  float a = sigf(alp[0]);
  float eneg = __expf(-vmax);
  float p[4]; float ps = 0.f;
  #pragma unroll
  for (int q=0;q<4;++q){
    p[q] = 0.f;
    if (d[q] >= 0.f) p[q] = ((km>>q)&1) ? __expf(d[q]-vmax) : eneg;
    ps += p[q];
  }
  #pragma unroll
  for (int off=1; off<64; off<<=1) ps += __shfl_xor(ps, off, 64);
  float inv = (1.f - a)/ps;
  float rs = 0.f;
  #pragma unroll
  for (int q=0;q<4;++q){
    int m = lane + q*64;
    if (m < NNODE){
      float Av = a*Aph[n*NNODE + m] + p[q]*inv;
      Abuf[(size_t)row*LSTR + m] = Av;
      rs += Av;
    }
  }
  if (lane == 0) Abuf[(size_t)row*LSTR + 207] = 0.f;
  #pragma unroll
  for (int off=1; off<64; off<<=1) rs += __shfl_xor(rs, off, 64);
  if (lane == 0) rsum[row] = rs;
}

__global__ __launch_bounds__(256) void k_lam(const float* __restrict__ rsum, float* __restrict__ lam){
  __shared__ float rv[256];
  int b = blockIdx.x, tid = threadIdx.x;
  rv[tid] = (tid < NNODE) ? rsum[b*NNODE+tid] : -1e30f;
  __syncthreads();
  for (int s=128;s>0;s>>=1){ if (tid<s) rv[tid]=fmaxf(rv[tid],rv[tid+s]); __syncthreads(); }
  if (tid==0) lam[b] = fmaxf(rv[0], 1.0f);
}

__global__ __launch_bounds__(256) void k_lap(float* __restrict__ Abuf, const float* __restrict__ lam){
  int idx = blockIdx.x*256 + threadIdx.x;
  if (idx >= NB*NNODE*LSTR) return;
  int b = idx / (NNODE*LSTR);
  int rem = idx % (NNODE*LSTR);
  int n = rem / LSTR, m = rem % LSTR;
  Abuf[idx] = 2.f*Abuf[idx]/lam[b] - (n==m ? 1.f : 0.f);
}

// causal conv(3) + GLU
__global__ __launch_bounds__(256) void k_tcn(const float* __restrict__ x,
    const float* __restrict__ w, const float* __restrict__ bcn, float* __restrict__ tfeat){
  int idx = blockIdx.x*256 + threadIdx.x;
  if (idx >= BTN*32) return;
  int o = idx & 31; int r = idx >> 5;
  int n = r % NNODE, bt = r / NNODE, t = bt % NT, b = bt / NT;
  float t0 = (t>=2)? x[((size_t)(b*NT+t-2)*NNODE+n)*NF] : 0.f;
  float t1 = (t>=1)? x[((size_t)(b*NT+t-1)*NNODE+n)*NF] : 0.f;
  float t2 = x[((size_t)(b*NT+t)*NNODE+n)*NF];
  float P = bcn[o]    + w[o*3]*t0       + w[o*3+1]*t1       + w[o*3+2]*t2;
  float Q = bcn[o+32] + w[(o+32)*3]*t0  + w[(o+32)*3+1]*t1  + w[(o+32)*3+2]*t2;
  tfeat[(size_t)r*32 + o] = P * sigf(Q);
}

__global__ __launch_bounds__(256) void k_thetaBC(const float* __restrict__ tfeat,
    const float* __restrict__ theta, float* __restrict__ P2, float* __restrict__ P1){
  __shared__ float thB[32][33], thC[32][33];
  __shared__ float tf[8][32];
  int tid = threadIdx.x;
  for (int i=tid; i<1024; i+=256){
    int f = i >> 5, o = i & 31;
    thB[o][f] = theta[1024+f*32+o]; thC[o][f] = theta[2048+f*32+o];
  }
  int rl = tid >> 5, o = tid & 31;
  int r = blockIdx.x*8 + rl;
  tf[rl][o] = tfeat[(size_t)r*32 + o];
  __syncthreads();
  float aB=0.f, aC=0.f;
  #pragma unroll
  for (int f=0; f<32; ++f){
    float t = tf[rl][f];
    aB += t*thB[o][f]; aC += t*thC[o][f];
  }
  int n = r % NNODE, bt = r / NNODE, t = bt % NT, b = bt / NT;
  size_t outi = (size_t)(b*NNODE+n)*G3 + t*32 + o;
  P2[outi]=aB; P1[outi]=aC;
}

__global__ __launch_bounds__(256) void k_thetaA(const float* __restrict__ tfeat,
    const float* __restrict__ theta, float* __restrict__ P1){
  __shared__ float thA[32][33];
  __shared__ float tf[8][32];
  int tid = threadIdx.x;
  for (int i=tid; i<1024; i+=256){
    int f = i >> 5, o = i & 31;
    thA[o][f] = theta[f*32+o] - theta[2048+f*32+o];
  }
  int rl = tid >> 5, o = tid & 31;
  int r = blockIdx.x*8 + rl;
  tf[rl][o] = tfeat[(size_t)r*32 + o];
  __syncthreads();
  float aA=0.f;
  #pragma unroll
  for (int f=0; f<32; ++f) aA += tf[rl][f]*thA[o][f];
  int n = r % NNODE, bt = r / NNODE, t = bt % NT, b = bt / NT;
  P1[(size_t)(b*NNODE+n)*G3 + t*32 + o] = aA;
}

// ---- fp32 128x128 GEMM (Chebyshev + ctxGX) ----
__global__ __launch_bounds__(256) void gemm128(
    const float* __restrict__ Ab, int lda, long long sA,
    const float* __restrict__ Bb, long long sB,
    const float* __restrict__ bias,
    const float* __restrict__ Yb, long long sY, float alphaV, float betaV, int do_relu,
    float* __restrict__ Cb, long long sC, int M, int kchunks){
  __shared__ float As[16][132];
  __shared__ float Bs[16][132];
  int bz = blockIdx.z;
  const float* A = Ab + (size_t)bz*sA;
  const float* B = Bb + (size_t)bz*sB;
  float* C = Cb + (size_t)bz*sC;
  int n0 = blockIdx.x*128, m0 = blockIdx.y*128;
  int tid = threadIdx.x, tx = tid & 15, ty = tid >> 4;
  float acc[8][8] = {};
  int ar = tid & 127, ak = (tid >> 7)*8;
  int bk = tid >> 4, bn = (tid & 15)*8;
  for (int kc=0; kc<kchunks; ++kc){
    int k0 = kc*16;
    int m = m0 + ar;
    if (m < M){
      const float* ap = A + (size_t)m*lda + k0 + ak;
      float4 v0 = *(const float4*)ap, v1 = *(const float4*)(ap+4);
      As[ak+0][ar]=v0.x; As[ak+1][ar]=v0.y; As[ak+2][ar]=v0.z; As[ak+3][ar]=v0.w;
      As[ak+4][ar]=v1.x; As[ak+5][ar]=v1.y; As[ak+6][ar]=v1.z; As[ak+7][ar]=v1.w;
    } else {
      #pragma unroll
      for (int j=0;j<8;++j) As[ak+j][ar]=0.f;
    }
    const float* bp = B + (size_t)(k0+bk)*384 + n0 + bn;
    float4 w0_ = *(const float4*)bp, w1_ = *(const float4*)(bp+4);
    *(float4*)&Bs[bk][bn] = w0_; *(float4*)&Bs[bk][bn+4] = w1_;
    __syncthreads();
    #pragma unroll
    for (int kk=0;kk<16;++kk){
      float4 a0 = *(const float4*)&As[kk][ty*8];
      float4 a1 = *(const float4*)&As[kk][ty*8+4];
      float4 b0 = *(const float4*)&Bs[kk][tx*4];
      float4 b1 = *(const float4*)&Bs[kk][64+tx*4];
      float av[8] = {a0.x,a0.y,a0.z,a0.w,a1.x,a1.y,a1.z,a1.w};
      float bv[8] = {b0.x,b0.y,b0.z,b0.w,b1.x,b1.y,b1.z,b1.w};
      #pragma unroll
      for (int i=0;i<8;++i)
        #pragma unroll
        for (int j=0;j<8;++j) acc[i][j] += av[i]*bv[j];
    }
    __syncthreads();
  }
  if (bias){
    float bl[4], bh_[4];
    #pragma unroll
    for (int j=0;j<4;++j){ bl[j]=bias[n0+tx*4+j]; bh_[j]=bias[n0+64+tx*4+j]; }
    #pragma unroll
    for (int i=0;i<8;++i){
      int m2 = m0 + ty*8 + i; if (m2 >= M) continue;
      float4 s0, s1;
      s0.x=acc[i][0]+bl[0]; s0.y=acc[i][1]+bl[1]; s0.z=acc[i][2]+bl[2]; s0.w=acc[i][3]+bl[3];
      s1.x=acc[i][4]+bh_[0]; s1.y=acc[i][5]+bh_[1]; s1.z=acc[i][6]+bh_[2]; s1.w=acc[i][7]+bh_[3];
      *(float4*)&C[(size_t)m2*384 + n0 + tx*4] = s0;
      *(float4*)&C[(size_t)m2*384 + n0 + 64 + tx*4] = s1;
    }
  } else {
    const float* Y = Yb + (size_t)bz*sY;
    #pragma unroll
    for (int i=0;i<8;++i){
      int m2 = m0 + ty*8 + i; if (m2 >= M) continue;
      const float* yr = Y + (size_t)m2*384;
      float* cr = C + (size_t)m2*384;
      float4 y0 = *(const float4*)(yr + n0 + tx*4);
      float4 y1 = *(const float4*)(yr + n0 + 64 + tx*4);
      float4 s0, s1;
      s0.x = alphaV*acc[i][0] + betaV*y0.x; s0.y = alphaV*acc[i][1] + betaV*y0.y;
      s0.z = alphaV*acc[i][2] + betaV*y0.z; s0.w = alphaV*acc[i][3] + betaV*y0.w;
      s1.x = alphaV*acc[i][4] + betaV*y1.x; s1.y = alphaV*acc[i][5] + betaV*y1.y;
      s1.z = alphaV*acc[i][6] + betaV*y1.z; s1.w = alphaV*acc[i][7] + betaV*y1.w;
      if (do_relu){
        s0.x=fmaxf(s0.x,0.f); s0.y=fmaxf(s0.y,0.f); s0.z=fmaxf(s0.z,0.f); s0.w=fmaxf(s0.w,0.f);
        s1.x=fmaxf(s1.x,0.f); s1.y=fmaxf(s1.y,0.f); s1.z=fmaxf(s1.z,0.f); s1.w=fmaxf(s1.w,0.f);
      }
      *(float4*)(cr + n0 + tx*4) = s0;
      *(float4*)(cr + n0 + 64 + tx*4) = s1;
    }
  }
}

// ===================== persistent MFMA encoder+decoder (v6) =====================
// 16 rows/block (grid 1656), 512 threads (8 waves). Wave w owns h-cols [16w,16w+16).
// Cross-step z-prefetch: step t computes z-part of step t+1 (independent MFMAs +
// HBM loads) between the h-GATE and the barrier. Decoder gx hoisted (loop-invariant).
#define GATEB(WH, WL, KS) \
    const int ko = (KS)*24; \
    short8 bRh = *(const short8*)(WH + ((size_t)(ko + w)*64 + lane)*8); \
    short8 bZh = *(const short8*)(WH + ((size_t)(ko + 8 + w)*64 + lane)*8); \
    short8 bNh = *(const short8*)(WH + ((size_t)(ko + 16 + w)*64 + lane)*8); \
    short8 bRl = *(const short8*)(WL + ((size_t)(ko + w)*64 + lane)*8); \
    short8 bZl = *(const short8*)(WL + ((size_t)(ko + 8 + w)*64 + lane)*8); \
    short8 bNl = *(const short8*)(WL + ((size_t)(ko + 16 + w)*64 + lane)*8);

#define ZPART(T, OR, OZ, ONZ) do{ \
    _Pragma("unroll") \
    for (int ks=0; ks<3; ++ks){ \
      GATEB(WFH, WFL, ks); \
      size_t zb = (((size_t)(T)*RG + R)*3 + ks)*512; \
      short8 ah = *(const short8*)(zfH + zb + lane*8); \
      short8 al = *(const short8*)(zfL + zb + lane*8); \
      mm3(ah, al, bRh, bRl, OR); \
      mm3(ah, al, bZh, bZl, OZ); \
      mm3(ah, al, bNh, bNl, ONZ); \
    } }while(0)

__global__ __launch_bounds__(512) void k_encdec(
    const short* __restrict__ zfH, const short* __restrict__ zfL,
    const short* __restrict__ WFH, const short* __restrict__ WFL,
    const float* __restrict__ bih, const float* __restrict__ bhh,
    const short* __restrict__ DFH, const short* __restrict__ DFL,
    const float* __restrict__ dbhh, const float* __restrict__ ctxGX,
    const float* __restrict__ w0, const float* __restrict__ ow,
    const float* __restrict__ ob, const float* __restrict__ pred0,
    float* __restrict__ preds_out){
  __shared__ __attribute__((aligned(16))) short hfH[4*512];   // [ks][lane*8+e]
  __shared__ __attribute__((aligned(16))) short hfL[4*512];
  __shared__ float psl[8][16];
  __shared__ float predl[16];
  int R = blockIdx.x, m0 = R*16;
  int tid = threadIdx.x;
  int w = tid >> 6, lane = tid & 63;
  int g = lane >> 4, c = lane & 15;
  int j = (w<<4) + c;
  float hreg[4] = {};
  for (int i = tid; i < 2048; i += 512){ hfH[i] = 0; hfL[i] = 0; }
  if (tid < 16) predl[tid] = pred0[m0 + tid];
  // epilogue write coords: h element (row, j) -> frag (ks_h, lane', e)
  int ksh = w >> 1, qh = 2*(w&1) + (c>>3), eh = c & 7;
  float birv = bih[j], bizv = bih[128+j], binv = bih[256+j];
  float bhrv = bhh[j], bhzv = bhh[128+j], bhnv = bhh[256+j];
  const accf4 AZERO = {};

  accf4 zR = AZERO, zZ = AZERO, zNZ = AZERO;
  ZPART(0, zR, zZ, zNZ);
  __syncthreads();

  // -------- encoder: 12 steps, z-part of t+1 prefetched during step t --------
  #pragma unroll 1
  for (int t = 0; t < NT; ++t){
    accf4 aR = zR, aZ = zZ, aNZ = zNZ, aNH = AZERO;
    #pragma unroll
    for (int ks=3; ks<7; ++ks){
      GATEB(WFH, WFL, ks);
      short8 ah = *(const short8*)&hfH[(ks-3)*512 + lane*8];
      short8 al = *(const short8*)&hfL[(ks-3)*512 + lane*8];
      mm3(ah, al, bRh, bRl, aR);
      mm3(ah, al, bZh, bZl, aZ);
      mm3(ah, al, bNh, bNl, aNH);
    }
    zR = AZERO; zZ = AZERO; zNZ = AZERO;
    if (t+1 < NT) ZPART(t+1, zR, zZ, zNZ);   // independent work: hides acc drain
    __syncthreads();   // all hf reads done
    #pragma unroll
    for (int i=0;i<4;++i){
      float r_ = sigf(aR[i] + birv + bhrv);
      float z_ = sigf(aZ[i] + bizv + bhzv);
      float n_ = tanhfast(aNZ[i] + binv + r_*(aNH[i] + bhnv));
      float hn = (1.f - z_)*n_ + z_*hreg[i];
      hreg[i] = hn;
      unsigned short hh = f2b(hn);
      int o = ksh*512 + ((g*4+i) + 16*qh)*8 + eh;
      hfH[o] = (short)hh;
      hfL[o] = (short)f2b(hn - b2f(hh));
    }
    __syncthreads();   // hf writes visible
  }

  // -------- decoder: 12 steps; gx is loop-invariant -> hoist --------
  float w0r = w0[j], w0z = w0[128+j], w0n = w0[256+j];
  float bhr = dbhh[j], bhz = dbhh[128+j], bhn = dbhh[256+j];
  float owj = ow[j];
  float obv = ob[0];
  float gxr[4], gxz[4], gxn[4];
  #pragma unroll
  for (int i=0;i<4;++i){
    int row = g*4 + i;
    const float* gx = ctxGX + (size_t)(m0+row)*384;
    gxr[i] = gx[j]; gxz[i] = gx[128+j]; gxn[i] = gx[256+j];
  }
  #pragma unroll 1
  for (int s = 0; s < NT; ++s){
    accf4 aR = AZERO, aZ = AZERO, aN = AZERO;
    #pragma unroll
    for (int ks=0; ks<4; ++ks){
      GATEB(DFH, DFL, ks);
      short8 ah = *(const short8*)&hfH[ks*512 + lane*8];
      short8 al = *(const short8*)&hfL[ks*512 + lane*8];
      mm3(ah, al, bRh, bRl, aR);
      mm3(ah, al, bZh, bZl, aZ);
      mm3(ah, al, bNh, bNl, aN);
    }
    __syncthreads();   // hf reads done; predl from prev step visible
    #pragma unroll
    for (int i=0;i<4;++i){
      int row = g*4 + i;
      float p = predl[row];
      float r_ = sigf(gxr[i] + p*w0r + aR[i] + bhr);
      float z_ = sigf(gxz[i] + p*w0z + aZ[i] + bhz);
      float n_ = tanhfast(gxn[i] + p*w0n + r_*(aN[i] + bhn));
      float hn = (1.f - z_)*n_ + z_*hreg[i];
      hreg[i] = hn;
      unsigned short hh = f2b(hn);
      int o = ksh*512 + (row + 16*qh)*8 + eh;
      hfH[o] = (short)hh;
      hfL[o] = (short)f2b(hn - b2f(hh));
      float psv = hn*owj;
      psv += __shfl_xor(psv, 1, 64);
      psv += __shfl_xor(psv, 2, 64);
      psv += __shfl_xor(psv, 4, 64);
      psv += __shfl_xor(psv, 8, 64);
      if (c == 0) psl[w][row] = psv;
    }
    __syncthreads();   // hf + psl writes visible
    if (tid < 16){
      float sm = obv;
      #pragma unroll
      for (int w2=0; w2<8; ++w2) sm += psl[w2][tid];
      predl[tid] = sm;
      preds_out[(size_t)s*ROWS + m0 + tid] = sm;
    }
    // predl consumed after next GATE's __syncthreads -> safe
  }
}

// fusion + attn gate; writes z pre-split into MFMA A-frag layout (zfH/zfL)
__global__ __launch_bounds__(256) void k_zbuild(const float* __restrict__ x,
    const float* __restrict__ S, const float* __restrict__ cw, const float* __restrict__ cb,
    const float* __restrict__ aw, const float* __restrict__ ab,
    short* __restrict__ zfH, short* __restrict__ zfL,
    float* __restrict__ ctx, float* __restrict__ pred0){
  __shared__ float cwl[416];
  __shared__ float cbl[32];
  __shared__ float awl[65];
  int tid = threadIdx.x;
  for (int i=tid; i<416; i+=256) cwl[i] = cw[i];
  if (tid < 32) cbl[tid] = cb[tid];
  if (tid < 65) awl[tid] = aw[tid];
  __syncthreads();
  int wid = tid >> 6, sel = (tid >> 5) & 1, hl = tid & 31;
  int r = blockIdx.x*8 + wid*2 + sel;
  int n = r % NNODE, bt = r / NNODE, t = bt % NT, b = bt / NT;
  const float* xr = x + (size_t)r*NF;
  float x0 = xr[0];
  float s_ = cbl[hl];
  #pragma unroll
  for (int f=0; f<13; ++f) s_ += xr[1+f]*cwl[hl*13+f];
  float ce = s_ > 0.f ? s_ : 0.f;
  float sv = S[(size_t)(b*NNODE+n)*G3 + t*32 + hl];
  float part = sv*awl[1+hl] + ce*awl[33+hl] + (hl==0 ? x0*awl[0] : 0.f);
  part += __shfl_xor(part, 1, 64);
  part += __shfl_xor(part, 2, 64);
  part += __shfl_xor(part, 4, 64);
  part += __shfl_xor(part, 8, 64);
  part += __shfl_xor(part, 16, 64);
  float attn = sigf(part + ab[0]);
  int i_ = r / NT, tau = r % NT;          // scrambled reshape (B*N, T, 65)
  int Rg = i_ >> 4, rowin = i_ & 15;
  size_t basez = (((size_t)tau*RG + Rg)*3)*512;
  #define ZPUT(L, V) do{ int l_=(L); int ks_=l_>>5, q_=(l_&31)>>3, e_=l_&7; \
      size_t o_ = basez + (size_t)ks_*512 + ((rowin + 16*q_)<<3) + e_; \
      float v_=(V); unsigned short hh_ = f2b(v_); \
      zfH[o_] = (short)hh_; zfL[o_] = (short)f2b(v_ - b2f(hh_)); }while(0)
  ZPUT(1+hl, sv*attn);
  ZPUT(33+hl, ce*attn);
  if (hl == 0) ZPUT(0, x0*attn);
  if (hl <= 30) ZPUT(65+hl, 0.f);   // pad l=65..95
  #undef ZPUT
  if (t == NT-1){
    ctx[(size_t)(b*NNODE+n)*32 + hl] = ce;
    if (hl == 0) pred0[b*NNODE+n] = x0;
  }
}

__global__ __launch_bounds__(256) void k_out(const float* __restrict__ preds, float* __restrict__ out){
  int idx = blockIdx.x*256 + threadIdx.x;
  if (idx >= NT*ROWS) return;
  int n = idx % NNODE;
  int t2 = idx / NNODE;
  int hor = t2 % NT;
  int b = t2 / NT;
  out[idx] = preds[(size_t)hor*ROWS + b*NNODE + n];
}

extern "C" void kernel_launch(void* const* d_in, const int* in_sizes, int n_in,
                              void* d_out, int out_size, void* d_ws, size_t ws_size,
                              hipStream_t stream){
  const float* x     = (const float*)d_in[0];
  const float* Aph   = (const float*)d_in[1];
  const float* fcw   = (const float*)d_in[2];
  const float* fcb   = (const float*)d_in[3];
  const float* alp   = (const float*)d_in[4];
  const float* cw    = (const float*)d_in[5];
  const float* cb    = (const float*)d_in[6];
  const float* tw    = (const float*)d_in[7];
  const float* tb    = (const float*)d_in[8];
  const float* theta = (const float*)d_in[9];
  const float* aw    = (const float*)d_in[10];
  const float* ab    = (const float*)d_in[11];
  const float* ewih  = (const float*)d_in[12];
  const float* ewhh  = (const float*)d_in[13];
  const float* ebih  = (const float*)d_in[14];
  const float* ebhh  = (const float*)d_in[15];
  const float* dwih  = (const float*)d_in[16];
  const float* dwhh  = (const float*)d_in[17];
  const float* dbih  = (const float*)d_in[18];
  const float* dbhh  = (const float*)d_in[19];
  const float* ow    = (const float*)d_in[20];
  const float* ob    = (const float*)d_in[21];
  float* out = (float*)d_out;

  const size_t SZ_CTX  = (size_t)ROWS*32;
  const size_t SZ_PRED = (size_t)ROWS;
  const size_t SZ_PREDS= (size_t)NT*ROWS;
  const size_t SZ_G    = (size_t)ROWS*G3;
  const size_t SZ_ABUF = (size_t)NB*NNODE*LSTR;
  const size_t SZ_EMB  = (size_t)ROWS*16;
  const size_t SZ_ZF   = (size_t)NT*RG*3*512;           // shorts per array
  const size_t SZ_UNION_FL = (2*SZ_ZF + 3) / 2;          // zfH+zfL in floats
  const size_t UNION_FL = (SZ_UNION_FL > 2*SZ_G) ? SZ_UNION_FL : 2*SZ_G;

  float* w = (float*)d_ws;
  size_t off = 0;
  auto alloc = [&](size_t nfl){ float* p = w + off; off += nfl; return p; };
  float* ctx   = alloc(SZ_CTX);
  float* pred  = alloc(SZ_PRED);
  float* preds = alloc(SZ_PREDS);
  float* Abuf  = alloc(SZ_ABUF);
  float* emb   = alloc(SZ_EMB);
  float* rsum  = alloc(SZ_PRED);
  float* lam   = alloc((size_t)NB);
  short* wS    = (short*)alloc(SH_TOTAL/2);
  float* wF    = alloc((size_t)FWT_TOTAL);
  float* Sslot = alloc(SZ_G);      // t_feat -> S -> ctxGX
  float* Uzone = alloc(UNION_FL);  // P1 | P2 during Chebyshev; zfH|zfL after
  float* P1 = Uzone;
  float* P2 = Uzone + SZ_G;
  short* zfH = (short*)Uzone;
  short* zfL = zfH + SZ_ZF;
  (void)n_in; (void)in_sizes;

  if (ws_size < off*sizeof(float)){    // tripwire: workspace too small
    k_sentinel<<<(out_size+255)/256, 256, 0, stream>>>(out, out_size);
    return;
  }

  const short* WFH = wS;
  const short* WFL = wS + NW_ENC;
  const short* DFH = wS + 2*NW_ENC;
  const short* DFL = wS + 2*NW_ENC + NW_DEC;
  float* dwihT = wF;
  float* w0    = wF + 32*384;

  k_prep<<<(PREP_TOTAL+255)/256, 256, 0, stream>>>(ewih, ewhh, dwih, dwhh, wS, wF);
  float* tfeat = Sslot;
  k_emb<<<(ROWS*16)/256, 256, 0, stream>>>(x, fcw, fcb, emb);
  k_adj<<<ROWS/4, 256, 0, stream>>>(emb, Aph, alp, Abuf, rsum);
  k_lam<<<NB, 256, 0, stream>>>(rsum, lam);
  k_lap<<<(NB*NNODE*LSTR)/256, 256, 0, stream>>>(Abuf, lam);
  k_tcn<<<(BTN*32)/256, 256, 0, stream>>>(x, tw, tb, tfeat);
  k_thetaBC<<<BTN/8, 256, 0, stream>>>(tfeat, theta, P2, P1);
  // P2 <- 2*(L @ P1) + P2
  gemm128<<<dim3(3, 2, NB), 256, 0, stream>>>(Abuf, LSTR, (long long)NNODE*LSTR,
      P1, (long long)NNODE*G3, nullptr,
      P2, (long long)NNODE*G3, 2.f, 1.f, 0,
      P2, (long long)NNODE*G3, NNODE, 13);
  k_thetaA<<<BTN/8, 256, 0, stream>>>(tfeat, theta, P1);
  // Sslot <- relu((L @ P2) + P1)
  gemm128<<<dim3(3, 2, NB), 256, 0, stream>>>(Abuf, LSTR, (long long)NNODE*LSTR,
      P2, (long long)NNODE*G3, nullptr,
      P1, (long long)NNODE*G3, 1.f, 1.f, 1,
      Sslot, (long long)NNODE*G3, NNODE, 13);
  k_zbuild<<<BTN/8, 256, 0, stream>>>(x, Sslot, cw, cb, aw, ab, zfH, zfL, ctx, pred);
  float* ctxGX = Sslot;  // S dead after zbuild
  gemm128<<<dim3(3, ROWS/128, 1), 256, 0, stream>>>(
      ctx, 32, 0, dwihT, 0, dbih,
      nullptr, 0, 1.f, 0.f, 0, ctxGX, 0, ROWS, 2);
  k_encdec<<<RG, 512, 0, stream>>>(zfH, zfL, WFH, WFL, ebih, ebhh,
      DFH, DFL, dbhh, ctxGX, w0, ow, ob, pred, preds);
  k_out<<<(NT*ROWS)/256, 256, 0, stream>>>(preds, out);
}

// Round 15
// 805.773 us; speedup vs baseline: 1.1223x; 1.1223x over previous
//
#include <hip/hip_runtime.h>
#include <math.h>

#define NB 128      // B
#define NT 12       // T
#define NNODE 207   // N
#define NF 14       // F
#define NH 128      // H
#define ROWS (NB*NNODE)      // 26496
#define BTN (NB*NT*NNODE)    // 317952
#define G3 (3*NH)            // 384
#define LSTR 208             // padded Laplacian row stride
#define RG (ROWS/16)         // 1656 row-groups of 16

typedef __attribute__((ext_vector_type(8))) short short8;   // 8 bf16 = 4 VGPR
typedef __attribute__((ext_vector_type(4))) float accf4;    // MFMA C/D

#define MFMA16 __builtin_amdgcn_mfma_f32_16x16x32_bf16

__device__ __forceinline__ float sigf(float x){ return 1.0f/(1.0f+__expf(-x)); }
__device__ __forceinline__ float tanhfast(float x){
  float e = __expf(2.f*x);
  return 1.f - 2.f/(e + 1.f);
}
__device__ __forceinline__ unsigned short f2b(float f){
  unsigned int u = __float_as_uint(f);
  return (unsigned short)((u + 0x7FFFu + ((u>>16)&1u)) >> 16);
}
__device__ __forceinline__ float b2f(unsigned short h){
  return __uint_as_float(((unsigned int)h) << 16);
}
// split-bf16 3-term product: hi*hi + lo*hi + hi*lo (lo*lo ~2^-16, negligible)
__device__ __forceinline__ void mm3(short8 ah, short8 al, short8 bh, short8 bl, accf4& acc){
  acc = MFMA16(ah, bh, acc, 0,0,0);
  acc = MFMA16(al, bh, acc, 0,0,0);
  acc = MFMA16(ah, bl, acc, 0,0,0);
}

__global__ __launch_bounds__(256) void k_sentinel(float* __restrict__ out, int n){
  int i = blockIdx.x*256 + threadIdx.x;
  if (i < n) out[i] = 12345.0f;
}

// ---- weight prep (fragment-layout bf16 hi/lo) ----
#define NW_ENC (7*24*64*8)   // 86016
#define NW_DEC (4*24*64*8)   // 49152
#define SH_TOTAL (2*NW_ENC + 2*NW_DEC)
#define FWT_TOTAL (32*384 + 384)
#define PREP_TOTAL (NW_ENC + NW_DEC + 32*384 + 384)
__global__ __launch_bounds__(256) void k_prep(const float* __restrict__ ewih,
    const float* __restrict__ ewhh, const float* __restrict__ dwih,
    const float* __restrict__ dwhh, short* __restrict__ ws, float* __restrict__ wf){
  int i = blockIdx.x*256 + threadIdx.x;
  if (i < NW_ENC){
    int e = i & 7, lane = (i>>3) & 63, ct = (i>>9) % 24, ks = i / 12288;
    int k = ks*32 + (lane>>4)*8 + e;
    int col = ct*16 + (lane&15);
    float wv = (k < 65) ? ewih[col*65 + k] : ((k < 96) ? 0.f : ewhh[col*128 + (k-96)]);
    unsigned short hi = f2b(wv);
    ws[i] = (short)hi;
    ws[NW_ENC + i] = (short)f2b(wv - b2f(hi));
  } else if (i < NW_ENC + NW_DEC){
    int j = i - NW_ENC;
    int e = j & 7, lane = (j>>3) & 63, ct = (j>>9) % 24, ks = j / 12288;
    int k = ks*32 + (lane>>4)*8 + e;
    int col = ct*16 + (lane&15);
    float wv = dwhh[col*128 + k];
    unsigned short hi = f2b(wv);
    ws[2*NW_ENC + j] = (short)hi;
    ws[2*NW_ENC + NW_DEC + j] = (short)f2b(wv - b2f(hi));
  } else if (i < NW_ENC + NW_DEC + 32*384){
    int j = i - (NW_ENC + NW_DEC); int k = j/384, n = j%384;
    wf[j] = dwih[n*33 + 1 + k];
  } else if (i < PREP_TOTAL){
    int n = i - (NW_ENC + NW_DEC + 32*384);
    wf[32*384 + n] = dwih[n*33];
  }
}

// emb = tanh(state * fc_w + fc_b)
__global__ __launch_bounds__(256) void k_emb(const float* __restrict__ x,
    const float* __restrict__ w, const float* __restrict__ b, float* __restrict__ emb){
  int idx = blockIdx.x*256 + threadIdx.x;
  if (idx >= ROWS*16) return;
  int j = idx & 15, row = idx >> 4;
  int bb = row / NNODE, n = row % NNODE;
  float s = x[((bb*NT + (NT-1))*NNODE + n)*NF];
  emb[idx] = tanhf(s*w[j] + b[j]);
}

// wave-per-row adjacency
__global__ __launch_bounds__(256) void k_adj(const float* __restrict__ emb,
    const float* __restrict__ Aph, const float* __restrict__ alp,
    float* __restrict__ Abuf, float* __restrict__ rsum){
  int wid = threadIdx.x >> 6, lane = threadIdx.x & 63;
  int row = blockIdx.x*4 + wid;
  int bb = row / NNODE, n = row % NNODE;
  const float4* er = (const float4*)(emb + (size_t)row*16);
  float4 e0 = er[0], e1 = er[1], e2 = er[2], e3 = er[3];
  float d[4];
  #pragma unroll
  for (int q=0;q<4;++q){
    int m = lane + q*64;
    float dd = -1.f;
    if (m < NNODE){
      const float4* em = (const float4*)(emb + (size_t)(bb*NNODE+m)*16);
      float4 m0 = em[0], m1 = em[1], m2 = em[2], m3 = em[3];
      dd = e0.x*m0.x + e0.y*m0.y + e0.z*m0.z + e0.w*m0.w
         + e1.x*m1.x + e1.y*m1.y + e1.z*m1.z + e1.w*m1.w
         + e2.x*m2.x + e2.y*m2.y + e2.z*m2.z + e2.w*m2.w
         + e3.x*m3.x + e3.y*m3.y + e3.z*m3.z + e3.w*m3.w;
      dd = dd > 0.f ? dd : 0.f;
    }
    d[q] = dd;
  }
  int km = 0;
  float vmax = 0.f;
  for (int it=0; it<10; ++it){
    float v = -1.f; int mi = 1<<20;
    #pragma unroll
    for (int q=0;q<4;++q){
      if (d[q] >= 0.f && !((km>>q)&1) && d[q] > v){ v = d[q]; mi = lane + q*64; }
    }
    #pragma unroll
    for (int off=1; off<64; off<<=1){
      float v2 = __shfl_xor(v, off, 64);
      int  i2 = __shfl_xor(mi, off, 64);
      if (v2 > v || (v2 == v && i2 < mi)){ v = v2; mi = i2; }
    }
    if (it == 0) vmax = v;
    if ((mi & 63) == lane) km |= 1 << (mi >> 6);
  }
  float a = sigf(alp[0]);
  float eneg = __expf(-vmax);
  float p[4]; float ps = 0.f;
  #pragma unroll
  for (int q=0;q<4;++q){
    p[q] = 0.f;
    if (d[q] >= 0.f) p[q] = ((km>>q)&1) ? __expf(d[q]-vmax) : eneg;
    ps += p[q];
  }
  #pragma unroll
  for (int off=1; off<64; off<<=1) ps += __shfl_xor(ps, off, 64);
  float inv = (1.f - a)/ps;
  float rs = 0.f;
  #pragma unroll
  for (int q=0;q<4;++q){
    int m = lane + q*64;
    if (m < NNODE){
      float Av = a*Aph[n*NNODE + m] + p[q]*inv;
      Abuf[(size_t)row*LSTR + m] = Av;
      rs += Av;
    }
  }
  if (lane == 0) Abuf[(size_t)row*LSTR + 207] = 0.f;
  #pragma unroll
  for (int off=1; off<64; off<<=1) rs += __shfl_xor(rs, off, 64);
  if (lane == 0) rsum[row] = rs;
}

__global__ __launch_bounds__(256) void k_lam(const float* __restrict__ rsum, float* __restrict__ lam){
  __shared__ float rv[256];
  int b = blockIdx.x, tid = threadIdx.x;
  rv[tid] = (tid < NNODE) ? rsum[b*NNODE+tid] : -1e30f;
  __syncthreads();
  for (int s=128;s>0;s>>=1){ if (tid<s) rv[tid]=fmaxf(rv[tid],rv[tid+s]); __syncthreads(); }
  if (tid==0) lam[b] = fmaxf(rv[0], 1.0f);
}

__global__ __launch_bounds__(256) void k_lap(float* __restrict__ Abuf, const float* __restrict__ lam){
  int idx = blockIdx.x*256 + threadIdx.x;
  if (idx >= NB*NNODE*LSTR) return;
  int b = idx / (NNODE*LSTR);
  int rem = idx % (NNODE*LSTR);
  int n = rem / LSTR, m = rem % LSTR;
  Abuf[idx] = 2.f*Abuf[idx]/lam[b] - (n==m ? 1.f : 0.f);
}

// causal conv(3) + GLU
__global__ __launch_bounds__(256) void k_tcn(const float* __restrict__ x,
    const float* __restrict__ w, const float* __restrict__ bcn, float* __restrict__ tfeat){
  int idx = blockIdx.x*256 + threadIdx.x;
  if (idx >= BTN*32) return;
  int o = idx & 31; int r = idx >> 5;
  int n = r % NNODE, bt = r / NNODE, t = bt % NT, b = bt / NT;
  float t0 = (t>=2)? x[((size_t)(b*NT+t-2)*NNODE+n)*NF] : 0.f;
  float t1 = (t>=1)? x[((size_t)(b*NT+t-1)*NNODE+n)*NF] : 0.f;
  float t2 = x[((size_t)(b*NT+t)*NNODE+n)*NF];
  float P = bcn[o]    + w[o*3]*t0       + w[o*3+1]*t1       + w[o*3+2]*t2;
  float Q = bcn[o+32] + w[(o+32)*3]*t0  + w[(o+32)*3+1]*t1  + w[(o+32)*3+2]*t2;
  tfeat[(size_t)r*32 + o] = P * sigf(Q);
}

__global__ __launch_bounds__(256) void k_thetaBC(const float* __restrict__ tfeat,
    const float* __restrict__ theta, float* __restrict__ P2, float* __restrict__ P1){
  __shared__ float thB[32][33], thC[32][33];
  __shared__ float tf[8][32];
  int tid = threadIdx.x;
  for (int i=tid; i<1024; i+=256){
    int f = i >> 5, o = i & 31;
    thB[o][f] = theta[1024+f*32+o]; thC[o][f] = theta[2048+f*32+o];
  }
  int rl = tid >> 5, o = tid & 31;
  int r = blockIdx.x*8 + rl;
  tf[rl][o] = tfeat[(size_t)r*32 + o];
  __syncthreads();
  float aB=0.f, aC=0.f;
  #pragma unroll
  for (int f=0; f<32; ++f){
    float t = tf[rl][f];
    aB += t*thB[o][f]; aC += t*thC[o][f];
  }
  int n = r % NNODE, bt = r / NNODE, t = bt % NT, b = bt / NT;
  size_t outi = (size_t)(b*NNODE+n)*G3 + t*32 + o;
  P2[outi]=aB; P1[outi]=aC;
}

__global__ __launch_bounds__(256) void k_thetaA(const float* __restrict__ tfeat,
    const float* __restrict__ theta, float* __restrict__ P1){
  __shared__ float thA[32][33];
  __shared__ float tf[8][32];
  int tid = threadIdx.x;
  for (int i=tid; i<1024; i+=256){
    int f = i >> 5, o = i & 31;
    thA[o][f] = theta[f*32+o] - theta[2048+f*32+o];
  }
  int rl = tid >> 5, o = tid & 31;
  int r = blockIdx.x*8 + rl;
  tf[rl][o] = tfeat[(size_t)r*32 + o];
  __syncthreads();
  float aA=0.f;
  #pragma unroll
  for (int f=0; f<32; ++f) aA += tf[rl][f]*thA[o][f];
  int n = r % NNODE, bt = r / NNODE, t = bt % NT, b = bt / NT;
  P1[(size_t)(b*NNODE+n)*G3 + t*32 + o] = aA;
}

// ---- fp32 128x128 GEMM (Chebyshev + ctxGX) ----
__global__ __launch_bounds__(256) void gemm128(
    const float* __restrict__ Ab, int lda, long long sA,
    const float* __restrict__ Bb, long long sB,
    const float* __restrict__ bias,
    const float* __restrict__ Yb, long long sY, float alphaV, float betaV, int do_relu,
    float* __restrict__ Cb, long long sC, int M, int kchunks){
  __shared__ float As[16][132];
  __shared__ float Bs[16][132];
  int bz = blockIdx.z;
  const float* A = Ab + (size_t)bz*sA;
  const float* B = Bb + (size_t)bz*sB;
  float* C = Cb + (size_t)bz*sC;
  int n0 = blockIdx.x*128, m0 = blockIdx.y*128;
  int tid = threadIdx.x, tx = tid & 15, ty = tid >> 4;
  float acc[8][8] = {};
  int ar = tid & 127, ak = (tid >> 7)*8;
  int bk = tid >> 4, bn = (tid & 15)*8;
  for (int kc=0; kc<kchunks; ++kc){
    int k0 = kc*16;
    int m = m0 + ar;
    if (m < M){
      const float* ap = A + (size_t)m*lda + k0 + ak;
      float4 v0 = *(const float4*)ap, v1 = *(const float4*)(ap+4);
      As[ak+0][ar]=v0.x; As[ak+1][ar]=v0.y; As[ak+2][ar]=v0.z; As[ak+3][ar]=v0.w;
      As[ak+4][ar]=v1.x; As[ak+5][ar]=v1.y; As[ak+6][ar]=v1.z; As[ak+7][ar]=v1.w;
    } else {
      #pragma unroll
      for (int j=0;j<8;++j) As[ak+j][ar]=0.f;
    }
    const float* bp = B + (size_t)(k0+bk)*384 + n0 + bn;
    float4 w0_ = *(const float4*)bp, w1_ = *(const float4*)(bp+4);
    *(float4*)&Bs[bk][bn] = w0_; *(float4*)&Bs[bk][bn+4] = w1_;
    __syncthreads();
    #pragma unroll
    for (int kk=0;kk<16;++kk){
      float4 a0 = *(const float4*)&As[kk][ty*8];
      float4 a1 = *(const float4*)&As[kk][ty*8+4];
      float4 b0 = *(const float4*)&Bs[kk][tx*4];
      float4 b1 = *(const float4*)&Bs[kk][64+tx*4];
      float av[8] = {a0.x,a0.y,a0.z,a0.w,a1.x,a1.y,a1.z,a1.w};
      float bv[8] = {b0.x,b0.y,b0.z,b0.w,b1.x,b1.y,b1.z,b1.w};
      #pragma unroll
      for (int i=0;i<8;++i)
        #pragma unroll
        for (int j=0;j<8;++j) acc[i][j] += av[i]*bv[j];
    }
    __syncthreads();
  }
  if (bias){
    float bl[4], bh_[4];
    #pragma unroll
    for (int j=0;j<4;++j){ bl[j]=bias[n0+tx*4+j]; bh_[j]=bias[n0+64+tx*4+j]; }
    #pragma unroll
    for (int i=0;i<8;++i){
      int m2 = m0 + ty*8 + i; if (m2 >= M) continue;
      float4 s0, s1;
      s0.x=acc[i][0]+bl[0]; s0.y=acc[i][1]+bl[1]; s0.z=acc[i][2]+bl[2]; s0.w=acc[i][3]+bl[3];
      s1.x=acc[i][4]+bh_[0]; s1.y=acc[i][5]+bh_[1]; s1.z=acc[i][6]+bh_[2]; s1.w=acc[i][7]+bh_[3];
      *(float4*)&C[(size_t)m2*384 + n0 + tx*4] = s0;
      *(float4*)&C[(size_t)m2*384 + n0 + 64 + tx*4] = s1;
    }
  } else {
    const float* Y = Yb + (size_t)bz*sY;
    #pragma unroll
    for (int i=0;i<8;++i){
      int m2 = m0 + ty*8 + i; if (m2 >= M) continue;
      const float* yr = Y + (size_t)m2*384;
      float* cr = C + (size_t)m2*384;
      float4 y0 = *(const float4*)(yr + n0 + tx*4);
      float4 y1 = *(const float4*)(yr + n0 + 64 + tx*4);
      float4 s0, s1;
      s0.x = alphaV*acc[i][0] + betaV*y0.x; s0.y = alphaV*acc[i][1] + betaV*y0.y;
      s0.z = alphaV*acc[i][2] + betaV*y0.z; s0.w = alphaV*acc[i][3] + betaV*y0.w;
      s1.x = alphaV*acc[i][4] + betaV*y1.x; s1.y = alphaV*acc[i][5] + betaV*y1.y;
      s1.z = alphaV*acc[i][6] + betaV*y1.z; s1.w = alphaV*acc[i][7] + betaV*y1.w;
      if (do_relu){
        s0.x=fmaxf(s0.x,0.f); s0.y=fmaxf(s0.y,0.f); s0.z=fmaxf(s0.z,0.f); s0.w=fmaxf(s0.w,0.f);
        s1.x=fmaxf(s1.x,0.f); s1.y=fmaxf(s1.y,0.f); s1.z=fmaxf(s1.z,0.f); s1.w=fmaxf(s1.w,0.f);
      }
      *(float4*)(cr + n0 + tx*4) = s0;
      *(float4*)(cr + n0 + 64 + tx*4) = s1;
    }
  }
}

// ===================== persistent MFMA encoder+decoder (v5 + micro) =====================
// 16 rows/block (grid 1656), 512 threads (8 waves). Wave w owns h-cols [16w,16w+16).
// R12 structure (best measured); micro: tanhfast + decoder gx hoisted.
#define GATEB(WH, WL, KS) \
    const int ko = (KS)*24; \
    short8 bRh = *(const short8*)(WH + ((size_t)(ko + w)*64 + lane)*8); \
    short8 bZh = *(const short8*)(WH + ((size_t)(ko + 8 + w)*64 + lane)*8); \
    short8 bNh = *(const short8*)(WH + ((size_t)(ko + 16 + w)*64 + lane)*8); \
    short8 bRl = *(const short8*)(WL + ((size_t)(ko + w)*64 + lane)*8); \
    short8 bZl = *(const short8*)(WL + ((size_t)(ko + 8 + w)*64 + lane)*8); \
    short8 bNl = *(const short8*)(WL + ((size_t)(ko + 16 + w)*64 + lane)*8);

__global__ __launch_bounds__(512) void k_encdec(
    const short* __restrict__ zfH, const short* __restrict__ zfL,
    const short* __restrict__ WFH, const short* __restrict__ WFL,
    const float* __restrict__ bih, const float* __restrict__ bhh,
    const short* __restrict__ DFH, const short* __restrict__ DFL,
    const float* __restrict__ dbhh, const float* __restrict__ ctxGX,
    const float* __restrict__ w0, const float* __restrict__ ow,
    const float* __restrict__ ob, const float* __restrict__ pred0,
    float* __restrict__ preds_out){
  __shared__ __attribute__((aligned(16))) short hfH[4*512];   // [ks][lane*8+e]
  __shared__ __attribute__((aligned(16))) short hfL[4*512];
  __shared__ float psl[8][16];
  __shared__ float predl[16];
  int R = blockIdx.x, m0 = R*16;
  int tid = threadIdx.x;
  int w = tid >> 6, lane = tid & 63;
  int g = lane >> 4, c = lane & 15;
  int j = (w<<4) + c;
  float hreg[4] = {};
  for (int i = tid; i < 2048; i += 512){ hfH[i] = 0; hfL[i] = 0; }
  if (tid < 16) predl[tid] = pred0[m0 + tid];
  // epilogue write coords: h element (row, j) -> frag (ks_h, lane', e)
  int ksh = w >> 1, qh = 2*(w&1) + (c>>3), eh = c & 7;
  float birv = bih[j], bizv = bih[128+j], binv = bih[256+j];
  float bhrv = bhh[j], bhzv = bhh[128+j], bhnv = bhh[256+j];
  __syncthreads();

  // -------- encoder: 12 steps --------
  for (int t = 0; t < NT; ++t){
    accf4 aR = {}, aZ = {}, aNZ = {}, aNH = {};
    #pragma unroll
    for (int ks=0; ks<3; ++ks){
      GATEB(WFH, WFL, ks);
      size_t zb = (((size_t)t*RG + R)*3 + ks)*512;
      short8 ah = *(const short8*)(zfH + zb + lane*8);
      short8 al = *(const short8*)(zfL + zb + lane*8);
      mm3(ah, al, bRh, bRl, aR);
      mm3(ah, al, bZh, bZl, aZ);
      mm3(ah, al, bNh, bNl, aNZ);
    }
    #pragma unroll
    for (int ks=3; ks<7; ++ks){
      GATEB(WFH, WFL, ks);
      short8 ah = *(const short8*)&hfH[(ks-3)*512 + lane*8];
      short8 al = *(const short8*)&hfL[(ks-3)*512 + lane*8];
      mm3(ah, al, bRh, bRl, aR);
      mm3(ah, al, bZh, bZl, aZ);
      mm3(ah, al, bNh, bNl, aNH);
    }
    __syncthreads();   // all hf reads done
    #pragma unroll
    for (int i=0;i<4;++i){
      float r_ = sigf(aR[i] + birv + bhrv);
      float z_ = sigf(aZ[i] + bizv + bhzv);
      float n_ = tanhfast(aNZ[i] + binv + r_*(aNH[i] + bhnv));
      float hn = (1.f - z_)*n_ + z_*hreg[i];
      hreg[i] = hn;
      unsigned short hh = f2b(hn);
      int o = ksh*512 + ((g*4+i) + 16*qh)*8 + eh;
      hfH[o] = (short)hh;
      hfL[o] = (short)f2b(hn - b2f(hh));
    }
    __syncthreads();   // hf writes visible
  }

  // -------- decoder: 12 steps; gx loop-invariant -> hoisted --------
  float w0r = w0[j], w0z = w0[128+j], w0n = w0[256+j];
  float bhr = dbhh[j], bhz = dbhh[128+j], bhn = dbhh[256+j];
  float owj = ow[j];
  float obv = ob[0];
  float gxr[4], gxz[4], gxn[4];
  #pragma unroll
  for (int i=0;i<4;++i){
    int row = g*4 + i;
    const float* gx = ctxGX + (size_t)(m0+row)*384;
    gxr[i] = gx[j]; gxz[i] = gx[128+j]; gxn[i] = gx[256+j];
  }
  for (int s = 0; s < NT; ++s){
    accf4 aR = {}, aZ = {}, aN = {};
    #pragma unroll
    for (int ks=0; ks<4; ++ks){
      GATEB(DFH, DFL, ks);
      short8 ah = *(const short8*)&hfH[ks*512 + lane*8];
      short8 al = *(const short8*)&hfL[ks*512 + lane*8];
      mm3(ah, al, bRh, bRl, aR);
      mm3(ah, al, bZh, bZl, aZ);
      mm3(ah, al, bNh, bNl, aN);
    }
    __syncthreads();   // hf reads done; predl from prev step visible
    #pragma unroll
    for (int i=0;i<4;++i){
      int row = g*4 + i;
      float p = predl[row];
      float r_ = sigf(gxr[i] + p*w0r + aR[i] + bhr);
      float z_ = sigf(gxz[i] + p*w0z + aZ[i] + bhz);
      float n_ = tanhfast(gxn[i] + p*w0n + r_*(aN[i] + bhn));
      float hn = (1.f - z_)*n_ + z_*hreg[i];
      hreg[i] = hn;
      unsigned short hh = f2b(hn);
      int o = ksh*512 + (row + 16*qh)*8 + eh;
      hfH[o] = (short)hh;
      hfL[o] = (short)f2b(hn - b2f(hh));
      float psv = hn*owj;
      psv += __shfl_xor(psv, 1, 64);
      psv += __shfl_xor(psv, 2, 64);
      psv += __shfl_xor(psv, 4, 64);
      psv += __shfl_xor(psv, 8, 64);
      if (c == 0) psl[w][row] = psv;
    }
    __syncthreads();   // hf + psl writes visible
    if (tid < 16){
      float sm = obv;
      #pragma unroll
      for (int w2=0; w2<8; ++w2) sm += psl[w2][tid];
      predl[tid] = sm;
      preds_out[(size_t)s*ROWS + m0 + tid] = sm;
    }
    // predl consumed after next GATE's __syncthreads -> safe
  }
}

// fusion + attn gate (v2): one block per (tau, row-group); assemble frag tile
// in LDS, coalesced dword writes to global. 16 rows x 16 lanes.
__global__ __launch_bounds__(256) void k_zbuild(const float* __restrict__ x,
    const float* __restrict__ S, const float* __restrict__ cw, const float* __restrict__ cb,
    const float* __restrict__ aw, const float* __restrict__ ab,
    short* __restrict__ zfH, short* __restrict__ zfL,
    float* __restrict__ ctx, float* __restrict__ pred0){
  __shared__ float cwl[416];
  __shared__ float cbl[32];
  __shared__ float awl[65];
  __shared__ short zH[1536];
  __shared__ short zL[1536];
  int tid = threadIdx.x;
  for (int i=tid; i<416; i+=256) cwl[i] = cw[i];
  if (tid < 32) cbl[tid] = cb[tid];
  if (tid < 65) awl[tid] = aw[tid];
  {
    int* zHi = (int*)zH; int* zLi = (int*)zL;
    for (int i=tid; i<768; i+=256){ zHi[i] = 0; zLi[i] = 0; }
  }
  __syncthreads();
  int bid = blockIdx.x;             // bid = tau*RG + Rg  (matches zf layout)
  int tau = bid / RG, Rg = bid % RG;
  int trow = tid >> 4, tl = tid & 15;
  int i_ = Rg*16 + trow;
  int r = i_*NT + tau;              // scrambled reshape inverse
  int n = r % NNODE, bt = r / NNODE, t = bt % NT, b = bt / NT;
  const float* xr = x + (size_t)r*NF;
  float x0 = xr[0];
  float ce0 = cbl[tl], ce1 = cbl[tl+16];
  #pragma unroll
  for (int f=0; f<13; ++f){
    float xv = xr[1+f];
    ce0 += xv*cwl[tl*13+f];
    ce1 += xv*cwl[(tl+16)*13+f];
  }
  ce0 = fmaxf(ce0, 0.f); ce1 = fmaxf(ce1, 0.f);
  const float* sr = S + (size_t)(b*NNODE+n)*G3 + t*32;
  float sv0 = sr[tl], sv1 = sr[tl+16];
  float part = sv0*awl[1+tl] + ce0*awl[33+tl]
             + sv1*awl[17+tl] + ce1*awl[49+tl]
             + (tl==0 ? x0*awl[0] : 0.f);
  part += __shfl_xor(part, 1, 64);
  part += __shfl_xor(part, 2, 64);
  part += __shfl_xor(part, 4, 64);
  part += __shfl_xor(part, 8, 64);
  float attn = sigf(part + ab[0]);
  #define ZPUT(L, V) do{ int l_=(L); int ks_=l_>>5, q_=(l_&31)>>3, e_=l_&7; \
      int o_ = ks_*512 + ((trow + 16*q_)<<3) + e_; \
      float v_=(V); unsigned short hh_ = f2b(v_); \
      zH[o_] = (short)hh_; zL[o_] = (short)f2b(v_ - b2f(hh_)); }while(0)
  ZPUT(1+tl, sv0*attn);
  ZPUT(17+tl, sv1*attn);
  ZPUT(33+tl, ce0*attn);
  ZPUT(49+tl, ce1*attn);              // tl=15 -> l=64 (c_emb ch 31)
  if (tl == 0) ZPUT(0, x0*attn);
  #undef ZPUT
  if (t == NT-1){
    float* cr = ctx + (size_t)(b*NNODE+n)*32;
    cr[tl] = ce0; cr[tl+16] = ce1;
    if (tl == 0) pred0[b*NNODE+n] = x0;
  }
  __syncthreads();
  size_t gb = (size_t)bid*1536;
  const int* zHi = (const int*)zH; const int* zLi = (const int*)zL;
  int* gH = (int*)(zfH + gb); int* gL = (int*)(zfL + gb);
  #pragma unroll
  for (int i=tid; i<768; i+=256){ gH[i] = zHi[i]; gL[i] = zLi[i]; }
}

__global__ __launch_bounds__(256) void k_out(const float* __restrict__ preds, float* __restrict__ out){
  int idx = blockIdx.x*256 + threadIdx.x;
  if (idx >= NT*ROWS) return;
  int n = idx % NNODE;
  int t2 = idx / NNODE;
  int hor = t2 % NT;
  int b = t2 / NT;
  out[idx] = preds[(size_t)hor*ROWS + b*NNODE + n];
}

extern "C" void kernel_launch(void* const* d_in, const int* in_sizes, int n_in,
                              void* d_out, int out_size, void* d_ws, size_t ws_size,
                              hipStream_t stream){
  const float* x     = (const float*)d_in[0];
  const float* Aph   = (const float*)d_in[1];
  const float* fcw   = (const float*)d_in[2];
  const float* fcb   = (const float*)d_in[3];
  const float* alp   = (const float*)d_in[4];
  const float* cw    = (const float*)d_in[5];
  const float* cb    = (const float*)d_in[6];
  const float* tw    = (const float*)d_in[7];
  const float* tb    = (const float*)d_in[8];
  const float* theta = (const float*)d_in[9];
  const float* aw    = (const float*)d_in[10];
  const float* ab    = (const float*)d_in[11];
  const float* ewih  = (const float*)d_in[12];
  const float* ewhh  = (const float*)d_in[13];
  const float* ebih  = (const float*)d_in[14];
  const float* ebhh  = (const float*)d_in[15];
  const float* dwih  = (const float*)d_in[16];
  const float* dwhh  = (const float*)d_in[17];
  const float* dbih  = (const float*)d_in[18];
  const float* dbhh  = (const float*)d_in[19];
  const float* ow    = (const float*)d_in[20];
  const float* ob    = (const float*)d_in[21];
  float* out = (float*)d_out;

  const size_t SZ_CTX  = (size_t)ROWS*32;
  const size_t SZ_PRED = (size_t)ROWS;
  const size_t SZ_PREDS= (size_t)NT*ROWS;
  const size_t SZ_G    = (size_t)ROWS*G3;
  const size_t SZ_ABUF = (size_t)NB*NNODE*LSTR;
  const size_t SZ_EMB  = (size_t)ROWS*16;
  const size_t SZ_ZF   = (size_t)NT*RG*3*512;           // shorts per array
  const size_t SZ_UNION_FL = (2*SZ_ZF + 3) / 2;          // zfH+zfL in floats
  const size_t UNION_FL = (SZ_UNION_FL > 2*SZ_G) ? SZ_UNION_FL : 2*SZ_G;

  float* w = (float*)d_ws;
  size_t off = 0;
  auto alloc = [&](size_t nfl){ float* p = w + off; off += nfl; return p; };
  float* ctx   = alloc(SZ_CTX);
  float* pred  = alloc(SZ_PRED);
  float* preds = alloc(SZ_PREDS);
  float* Abuf  = alloc(SZ_ABUF);
  float* emb   = alloc(SZ_EMB);
  float* rsum  = alloc(SZ_PRED);
  float* lam   = alloc((size_t)NB);
  short* wS    = (short*)alloc(SH_TOTAL/2);
  float* wF    = alloc((size_t)FWT_TOTAL);
  float* Sslot = alloc(SZ_G);      // t_feat -> S -> ctxGX
  float* Uzone = alloc(UNION_FL);  // P1 | P2 during Chebyshev; zfH|zfL after
  float* P1 = Uzone;
  float* P2 = Uzone + SZ_G;
  short* zfH = (short*)Uzone;
  short* zfL = zfH + SZ_ZF;
  (void)n_in; (void)in_sizes;

  if (ws_size < off*sizeof(float)){    // tripwire: workspace too small
    k_sentinel<<<(out_size+255)/256, 256, 0, stream>>>(out, out_size);
    return;
  }

  const short* WFH = wS;
  const short* WFL = wS + NW_ENC;
  const short* DFH = wS + 2*NW_ENC;
  const short* DFL = wS + 2*NW_ENC + NW_DEC;
  float* dwihT = wF;
  float* w0    = wF + 32*384;

  k_prep<<<(PREP_TOTAL+255)/256, 256, 0, stream>>>(ewih, ewhh, dwih, dwhh, wS, wF);
  float* tfeat = Sslot;
  k_emb<<<(ROWS*16)/256, 256, 0, stream>>>(x, fcw, fcb, emb);
  k_adj<<<ROWS/4, 256, 0, stream>>>(emb, Aph, alp, Abuf, rsum);
  k_lam<<<NB, 256, 0, stream>>>(rsum, lam);
  k_lap<<<(NB*NNODE*LSTR)/256, 256, 0, stream>>>(Abuf, lam);
  k_tcn<<<(BTN*32)/256, 256, 0, stream>>>(x, tw, tb, tfeat);
  k_thetaBC<<<BTN/8, 256, 0, stream>>>(tfeat, theta, P2, P1);
  // P2 <- 2*(L @ P1) + P2
  gemm128<<<dim3(3, 2, NB), 256, 0, stream>>>(Abuf, LSTR, (long long)NNODE*LSTR,
      P1, (long long)NNODE*G3, nullptr,
      P2, (long long)NNODE*G3, 2.f, 1.f, 0,
      P2, (long long)NNODE*G3, NNODE, 13);
  k_thetaA<<<BTN/8, 256, 0, stream>>>(tfeat, theta, P1);
  // Sslot <- relu((L @ P2) + P1)
  gemm128<<<dim3(3, 2, NB), 256, 0, stream>>>(Abuf, LSTR, (long long)NNODE*LSTR,
      P2, (long long)NNODE*G3, nullptr,
      P1, (long long)NNODE*G3, 1.f, 1.f, 1,
      Sslot, (long long)NNODE*G3, NNODE, 13);
  k_zbuild<<<NT*RG, 256, 0, stream>>>(x, Sslot, cw, cb, aw, ab, zfH, zfL, ctx, pred);
  float* ctxGX = Sslot;  // S dead after zbuild
  gemm128<<<dim3(3, ROWS/128, 1), 256, 0, stream>>>(
      ctx, 32, 0, dwihT, 0, dbih,
      nullptr, 0, 1.f, 0.f, 0, ctxGX, 0, ROWS, 2);
  k_encdec<<<RG, 512, 0, stream>>>(zfH, zfL, WFH, WFL, ebih, ebhh,
      DFH, DFL, dbhh, ctxGX, w0, ow, ob, pred, preds);
  k_out<<<(NT*ROWS)/256, 256, 0, stream>>>(preds, out);
}

// Round 16
// 742.670 us; speedup vs baseline: 1.2177x; 1.0850x over previous
//
#include <hip/hip_runtime.h>
#include <math.h>

#define NB 128      // B
#define NT 12       // T
#define NNODE 207   // N
#define NF 14       // F
#define NH 128      // H
#define ROWS (NB*NNODE)      // 26496
#define BTN (NB*NT*NNODE)    // 317952
#define G3 (3*NH)            // 384
#define LSTR 208             // padded Laplacian row stride
#define RG (ROWS/16)         // 1656 row-groups of 16

typedef __attribute__((ext_vector_type(8))) short short8;   // 8 bf16 = 4 VGPR
typedef __attribute__((ext_vector_type(4))) float accf4;    // MFMA C/D

#define MFMA16 __builtin_amdgcn_mfma_f32_16x16x32_bf16

__device__ __forceinline__ float sigf(float x){ return 1.0f/(1.0f+__expf(-x)); }
__device__ __forceinline__ float tanhfast(float x){
  float e = __expf(2.f*x);
  return 1.f - 2.f/(e + 1.f);
}
__device__ __forceinline__ unsigned short f2b(float f){
  unsigned int u = __float_as_uint(f);
  return (unsigned short)((u + 0x7FFFu + ((u>>16)&1u)) >> 16);
}
__device__ __forceinline__ float b2f(unsigned short h){
  return __uint_as_float(((unsigned int)h) << 16);
}
// split-A x single-bf16-B: (ah+al) * bh  (weights RNE bf16; h/z keep split)
__device__ __forceinline__ void mm2(short8 ah, short8 al, short8 bh, accf4& acc){
  acc = MFMA16(ah, bh, acc, 0,0,0);
  acc = MFMA16(al, bh, acc, 0,0,0);
}

__global__ __launch_bounds__(256) void k_sentinel(float* __restrict__ out, int n){
  int i = blockIdx.x*256 + threadIdx.x;
  if (i < n) out[i] = 12345.0f;
}

// ---- weight prep (fragment-layout bf16 hi; lo arrays retained but unused) ----
#define NW_ENC (7*24*64*8)   // 86016
#define NW_DEC (4*24*64*8)   // 49152
#define SH_TOTAL (2*NW_ENC + 2*NW_DEC)
#define FWT_TOTAL (32*384 + 384)
#define PREP_TOTAL (NW_ENC + NW_DEC + 32*384 + 384)
__global__ __launch_bounds__(256) void k_prep(const float* __restrict__ ewih,
    const float* __restrict__ ewhh, const float* __restrict__ dwih,
    const float* __restrict__ dwhh, short* __restrict__ ws, float* __restrict__ wf){
  int i = blockIdx.x*256 + threadIdx.x;
  if (i < NW_ENC){
    int e = i & 7, lane = (i>>3) & 63, ct = (i>>9) % 24, ks = i / 12288;
    int k = ks*32 + (lane>>4)*8 + e;
    int col = ct*16 + (lane&15);
    float wv = (k < 65) ? ewih[col*65 + k] : ((k < 96) ? 0.f : ewhh[col*128 + (k-96)]);
    unsigned short hi = f2b(wv);
    ws[i] = (short)hi;
    ws[NW_ENC + i] = (short)f2b(wv - b2f(hi));
  } else if (i < NW_ENC + NW_DEC){
    int j = i - NW_ENC;
    int e = j & 7, lane = (j>>3) & 63, ct = (j>>9) % 24, ks = j / 12288;
    int k = ks*32 + (lane>>4)*8 + e;
    int col = ct*16 + (lane&15);
    float wv = dwhh[col*128 + k];
    unsigned short hi = f2b(wv);
    ws[2*NW_ENC + j] = (short)hi;
    ws[2*NW_ENC + NW_DEC + j] = (short)f2b(wv - b2f(hi));
  } else if (i < NW_ENC + NW_DEC + 32*384){
    int j = i - (NW_ENC + NW_DEC); int k = j/384, n = j%384;
    wf[j] = dwih[n*33 + 1 + k];
  } else if (i < PREP_TOTAL){
    int n = i - (NW_ENC + NW_DEC + 32*384);
    wf[32*384 + n] = dwih[n*33];
  }
}

// emb = tanh(state * fc_w + fc_b)
__global__ __launch_bounds__(256) void k_emb(const float* __restrict__ x,
    const float* __restrict__ w, const float* __restrict__ b, float* __restrict__ emb){
  int idx = blockIdx.x*256 + threadIdx.x;
  if (idx >= ROWS*16) return;
  int j = idx & 15, row = idx >> 4;
  int bb = row / NNODE, n = row % NNODE;
  float s = x[((bb*NT + (NT-1))*NNODE + n)*NF];
  emb[idx] = tanhf(s*w[j] + b[j]);
}

// wave-per-row adjacency
__global__ __launch_bounds__(256) void k_adj(const float* __restrict__ emb,
    const float* __restrict__ Aph, const float* __restrict__ alp,
    float* __restrict__ Abuf, float* __restrict__ rsum){
  int wid = threadIdx.x >> 6, lane = threadIdx.x & 63;
  int row = blockIdx.x*4 + wid;
  int bb = row / NNODE, n = row % NNODE;
  const float4* er = (const float4*)(emb + (size_t)row*16);
  float4 e0 = er[0], e1 = er[1], e2 = er[2], e3 = er[3];
  float d[4];
  #pragma unroll
  for (int q=0;q<4;++q){
    int m = lane + q*64;
    float dd = -1.f;
    if (m < NNODE){
      const float4* em = (const float4*)(emb + (size_t)(bb*NNODE+m)*16);
      float4 m0 = em[0], m1 = em[1], m2 = em[2], m3 = em[3];
      dd = e0.x*m0.x + e0.y*m0.y + e0.z*m0.z + e0.w*m0.w
         + e1.x*m1.x + e1.y*m1.y + e1.z*m1.z + e1.w*m1.w
         + e2.x*m2.x + e2.y*m2.y + e2.z*m2.z + e2.w*m2.w
         + e3.x*m3.x + e3.y*m3.y + e3.z*m3.z + e3.w*m3.w;
      dd = dd > 0.f ? dd : 0.f;
    }
    d[q] = dd;
  }
  int km = 0;
  float vmax = 0.f;
  for (int it=0; it<10; ++it){
    float v = -1.f; int mi = 1<<20;
    #pragma unroll
    for (int q=0;q<4;++q){
      if (d[q] >= 0.f && !((km>>q)&1) && d[q] > v){ v = d[q]; mi = lane + q*64; }
    }
    #pragma unroll
    for (int off=1; off<64; off<<=1){
      float v2 = __shfl_xor(v, off, 64);
      int  i2 = __shfl_xor(mi, off, 64);
      if (v2 > v || (v2 == v && i2 < mi)){ v = v2; mi = i2; }
    }
    if (it == 0) vmax = v;
    if ((mi & 63) == lane) km |= 1 << (mi >> 6);
  }
  float a = sigf(alp[0]);
  float eneg = __expf(-vmax);
  float p[4]; float ps = 0.f;
  #pragma unroll
  for (int q=0;q<4;++q){
    p[q] = 0.f;
    if (d[q] >= 0.f) p[q] = ((km>>q)&1) ? __expf(d[q]-vmax) : eneg;
    ps += p[q];
  }
  #pragma unroll
  for (int off=1; off<64; off<<=1) ps += __shfl_xor(ps, off, 64);
  float inv = (1.f - a)/ps;
  float rs = 0.f;
  #pragma unroll
  for (int q=0;q<4;++q){
    int m = lane + q*64;
    if (m < NNODE){
      float Av = a*Aph[n*NNODE + m] + p[q]*inv;
      Abuf[(size_t)row*LSTR + m] = Av;
      rs += Av;
    }
  }
  if (lane == 0) Abuf[(size_t)row*LSTR + 207] = 0.f;
  #pragma unroll
  for (int off=1; off<64; off<<=1) rs += __shfl_xor(rs, off, 64);
  if (lane == 0) rsum[row] = rs;
}

__global__ __launch_bounds__(256) void k_lam(const float* __restrict__ rsum, float* __restrict__ lam){
  __shared__ float rv[256];
  int b = blockIdx.x, tid = threadIdx.x;
  rv[tid] = (tid < NNODE) ? rsum[b*NNODE+tid] : -1e30f;
  __syncthreads();
  for (int s=128;s>0;s>>=1){ if (tid<s) rv[tid]=fmaxf(rv[tid],rv[tid+s]); __syncthreads(); }
  if (tid==0) lam[b] = fmaxf(rv[0], 1.0f);
}

__global__ __launch_bounds__(256) void k_lap(float* __restrict__ Abuf, const float* __restrict__ lam){
  int idx = blockIdx.x*256 + threadIdx.x;
  if (idx >= NB*NNODE*LSTR) return;
  int b = idx / (NNODE*LSTR);
  int rem = idx % (NNODE*LSTR);
  int n = rem / LSTR, m = rem % LSTR;
  Abuf[idx] = 2.f*Abuf[idx]/lam[b] - (n==m ? 1.f : 0.f);
}

// causal conv(3) + GLU
__global__ __launch_bounds__(256) void k_tcn(const float* __restrict__ x,
    const float* __restrict__ w, const float* __restrict__ bcn, float* __restrict__ tfeat){
  int idx = blockIdx.x*256 + threadIdx.x;
  if (idx >= BTN*32) return;
  int o = idx & 31; int r = idx >> 5;
  int n = r % NNODE, bt = r / NNODE, t = bt % NT, b = bt / NT;
  float t0 = (t>=2)? x[((size_t)(b*NT+t-2)*NNODE+n)*NF] : 0.f;
  float t1 = (t>=1)? x[((size_t)(b*NT+t-1)*NNODE+n)*NF] : 0.f;
  float t2 = x[((size_t)(b*NT+t)*NNODE+n)*NF];
  float P = bcn[o]    + w[o*3]*t0       + w[o*3+1]*t1       + w[o*3+2]*t2;
  float Q = bcn[o+32] + w[(o+32)*3]*t0  + w[(o+32)*3+1]*t1  + w[(o+32)*3+2]*t2;
  tfeat[(size_t)r*32 + o] = P * sigf(Q);
}

__global__ __launch_bounds__(256) void k_thetaBC(const float* __restrict__ tfeat,
    const float* __restrict__ theta, float* __restrict__ P2, float* __restrict__ P1){
  __shared__ float thB[32][33], thC[32][33];
  __shared__ float tf[8][32];
  int tid = threadIdx.x;
  for (int i=tid; i<1024; i+=256){
    int f = i >> 5, o = i & 31;
    thB[o][f] = theta[1024+f*32+o]; thC[o][f] = theta[2048+f*32+o];
  }
  int rl = tid >> 5, o = tid & 31;
  int r = blockIdx.x*8 + rl;
  tf[rl][o] = tfeat[(size_t)r*32 + o];
  __syncthreads();
  float aB=0.f, aC=0.f;
  #pragma unroll
  for (int f=0; f<32; ++f){
    float t = tf[rl][f];
    aB += t*thB[o][f]; aC += t*thC[o][f];
  }
  int n = r % NNODE, bt = r / NNODE, t = bt % NT, b = bt / NT;
  size_t outi = (size_t)(b*NNODE+n)*G3 + t*32 + o;
  P2[outi]=aB; P1[outi]=aC;
}

__global__ __launch_bounds__(256) void k_thetaA(const float* __restrict__ tfeat,
    const float* __restrict__ theta, float* __restrict__ P1){
  __shared__ float thA[32][33];
  __shared__ float tf[8][32];
  int tid = threadIdx.x;
  for (int i=tid; i<1024; i+=256){
    int f = i >> 5, o = i & 31;
    thA[o][f] = theta[f*32+o] - theta[2048+f*32+o];
  }
  int rl = tid >> 5, o = tid & 31;
  int r = blockIdx.x*8 + rl;
  tf[rl][o] = tfeat[(size_t)r*32 + o];
  __syncthreads();
  float aA=0.f;
  #pragma unroll
  for (int f=0; f<32; ++f) aA += tf[rl][f]*thA[o][f];
  int n = r % NNODE, bt = r / NNODE, t = bt % NT, b = bt / NT;
  P1[(size_t)(b*NNODE+n)*G3 + t*32 + o] = aA;
}

// ---- fp32 128x128 GEMM (Chebyshev + ctxGX) ----
__global__ __launch_bounds__(256) void gemm128(
    const float* __restrict__ Ab, int lda, long long sA,
    const float* __restrict__ Bb, long long sB,
    const float* __restrict__ bias,
    const float* __restrict__ Yb, long long sY, float alphaV, float betaV, int do_relu,
    float* __restrict__ Cb, long long sC, int M, int kchunks){
  __shared__ float As[16][132];
  __shared__ float Bs[16][132];
  int bz = blockIdx.z;
  const float* A = Ab + (size_t)bz*sA;
  const float* B = Bb + (size_t)bz*sB;
  float* C = Cb + (size_t)bz*sC;
  int n0 = blockIdx.x*128, m0 = blockIdx.y*128;
  int tid = threadIdx.x, tx = tid & 15, ty = tid >> 4;
  float acc[8][8] = {};
  int ar = tid & 127, ak = (tid >> 7)*8;
  int bk = tid >> 4, bn = (tid & 15)*8;
  for (int kc=0; kc<kchunks; ++kc){
    int k0 = kc*16;
    int m = m0 + ar;
    if (m < M){
      const float* ap = A + (size_t)m*lda + k0 + ak;
      float4 v0 = *(const float4*)ap, v1 = *(const float4*)(ap+4);
      As[ak+0][ar]=v0.x; As[ak+1][ar]=v0.y; As[ak+2][ar]=v0.z; As[ak+3][ar]=v0.w;
      As[ak+4][ar]=v1.x; As[ak+5][ar]=v1.y; As[ak+6][ar]=v1.z; As[ak+7][ar]=v1.w;
    } else {
      #pragma unroll
      for (int j=0;j<8;++j) As[ak+j][ar]=0.f;
    }
    const float* bp = B + (size_t)(k0+bk)*384 + n0 + bn;
    float4 w0_ = *(const float4*)bp, w1_ = *(const float4*)(bp+4);
    *(float4*)&Bs[bk][bn] = w0_; *(float4*)&Bs[bk][bn+4] = w1_;
    __syncthreads();
    #pragma unroll
    for (int kk=0;kk<16;++kk){
      float4 a0 = *(const float4*)&As[kk][ty*8];
      float4 a1 = *(const float4*)&As[kk][ty*8+4];
      float4 b0 = *(const float4*)&Bs[kk][tx*4];
      float4 b1 = *(const float4*)&Bs[kk][64+tx*4];
      float av[8] = {a0.x,a0.y,a0.z,a0.w,a1.x,a1.y,a1.z,a1.w};
      float bv[8] = {b0.x,b0.y,b0.z,b0.w,b1.x,b1.y,b1.z,b1.w};
      #pragma unroll
      for (int i=0;i<8;++i)
        #pragma unroll
        for (int j=0;j<8;++j) acc[i][j] += av[i]*bv[j];
    }
    __syncthreads();
  }
  if (bias){
    float bl[4], bh_[4];
    #pragma unroll
    for (int j=0;j<4;++j){ bl[j]=bias[n0+tx*4+j]; bh_[j]=bias[n0+64+tx*4+j]; }
    #pragma unroll
    for (int i=0;i<8;++i){
      int m2 = m0 + ty*8 + i; if (m2 >= M) continue;
      float4 s0, s1;
      s0.x=acc[i][0]+bl[0]; s0.y=acc[i][1]+bl[1]; s0.z=acc[i][2]+bl[2]; s0.w=acc[i][3]+bl[3];
      s1.x=acc[i][4]+bh_[0]; s1.y=acc[i][5]+bh_[1]; s1.z=acc[i][6]+bh_[2]; s1.w=acc[i][7]+bh_[3];
      *(float4*)&C[(size_t)m2*384 + n0 + tx*4] = s0;
      *(float4*)&C[(size_t)m2*384 + n0 + 64 + tx*4] = s1;
    }
  } else {
    const float* Y = Yb + (size_t)bz*sY;
    #pragma unroll
    for (int i=0;i<8;++i){
      int m2 = m0 + ty*8 + i; if (m2 >= M) continue;
      const float* yr = Y + (size_t)m2*384;
      float* cr = C + (size_t)m2*384;
      float4 y0 = *(const float4*)(yr + n0 + tx*4);
      float4 y1 = *(const float4*)(yr + n0 + 64 + tx*4);
      float4 s0, s1;
      s0.x = alphaV*acc[i][0] + betaV*y0.x; s0.y = alphaV*acc[i][1] + betaV*y0.y;
      s0.z = alphaV*acc[i][2] + betaV*y0.z; s0.w = alphaV*acc[i][3] + betaV*y0.w;
      s1.x = alphaV*acc[i][4] + betaV*y1.x; s1.y = alphaV*acc[i][5] + betaV*y1.y;
      s1.z = alphaV*acc[i][6] + betaV*y1.z; s1.w = alphaV*acc[i][7] + betaV*y1.w;
      if (do_relu){
        s0.x=fmaxf(s0.x,0.f); s0.y=fmaxf(s0.y,0.f); s0.z=fmaxf(s0.z,0.f); s0.w=fmaxf(s0.w,0.f);
        s1.x=fmaxf(s1.x,0.f); s1.y=fmaxf(s1.y,0.f); s1.z=fmaxf(s1.z,0.f); s1.w=fmaxf(s1.w,0.f);
      }
      *(float4*)(cr + n0 + tx*4) = s0;
      *(float4*)(cr + n0 + 64 + tx*4) = s1;
    }
  }
}

// ===================== persistent MFMA encoder+decoder (v7) =====================
// 16 rows/block (grid 1656), 512 threads (8 waves). Wave w owns h-cols [16w,16w+16).
// mm2: weights single bf16 (RNE); h/z split. Double-buffered hf -> 1 barrier per
// encoder step. tanhfast; decoder gx hoisted.
#define GATEB(WH, KS) \
    const int ko = (KS)*24; \
    short8 bRh = *(const short8*)(WH + ((size_t)(ko + w)*64 + lane)*8); \
    short8 bZh = *(const short8*)(WH + ((size_t)(ko + 8 + w)*64 + lane)*8); \
    short8 bNh = *(const short8*)(WH + ((size_t)(ko + 16 + w)*64 + lane)*8);

__global__ __launch_bounds__(512) void k_encdec(
    const short* __restrict__ zfH, const short* __restrict__ zfL,
    const short* __restrict__ WFH,
    const float* __restrict__ bih, const float* __restrict__ bhh,
    const short* __restrict__ DFH,
    const float* __restrict__ dbhh, const float* __restrict__ ctxGX,
    const float* __restrict__ w0, const float* __restrict__ ow,
    const float* __restrict__ ob, const float* __restrict__ pred0,
    float* __restrict__ preds_out){
  __shared__ __attribute__((aligned(16))) short hfH[2*4*512];   // [buf][ks][lane*8+e]
  __shared__ __attribute__((aligned(16))) short hfL[2*4*512];
  __shared__ float psl[8][16];
  __shared__ float predl[16];
  int R = blockIdx.x, m0 = R*16;
  int tid = threadIdx.x;
  int w = tid >> 6, lane = tid & 63;
  int g = lane >> 4, c = lane & 15;
  int j = (w<<4) + c;
  float hreg[4] = {};
  for (int i = tid; i < 4096; i += 512){ hfH[i] = 0; hfL[i] = 0; }
  if (tid < 16) predl[tid] = pred0[m0 + tid];
  // epilogue write coords: h element (row, j) -> frag (ks_h, lane', e)
  int ksh = w >> 1, qh = 2*(w&1) + (c>>3), eh = c & 7;
  int epo = ksh*512 + ((g*4) + 16*qh)*8 + eh;   // + i*8 per row
  float birv = bih[j], bizv = bih[128+j], binv = bih[256+j];
  float bhrv = bhh[j], bhzv = bhh[128+j], bhnv = bhh[256+j];
  __syncthreads();

  int cur = 0;
  // -------- encoder: 12 steps, 1 barrier each (hf double-buffered) --------
  for (int t = 0; t < NT; ++t){
    accf4 aR = {}, aZ = {}, aNZ = {}, aNH = {};
    #pragma unroll
    for (int ks=0; ks<3; ++ks){
      GATEB(WFH, ks);
      size_t zb = (((size_t)t*RG + R)*3 + ks)*512;
      short8 ah = *(const short8*)(zfH + zb + lane*8);
      short8 al = *(const short8*)(zfL + zb + lane*8);
      mm2(ah, al, bRh, aR);
      mm2(ah, al, bZh, aZ);
      mm2(ah, al, bNh, aNZ);
    }
    #pragma unroll
    for (int ks=3; ks<7; ++ks){
      GATEB(WFH, ks);
      short8 ah = *(const short8*)&hfH[cur*2048 + (ks-3)*512 + lane*8];
      short8 al = *(const short8*)&hfL[cur*2048 + (ks-3)*512 + lane*8];
      mm2(ah, al, bRh, aR);
      mm2(ah, al, bZh, aZ);
      mm2(ah, al, bNh, aNH);
    }
    int nxt = cur ^ 1;
    #pragma unroll
    for (int i=0;i<4;++i){
      float r_ = sigf(aR[i] + birv + bhrv);
      float z_ = sigf(aZ[i] + bizv + bhzv);
      float n_ = tanhfast(aNZ[i] + binv + r_*(aNH[i] + bhnv));
      float hn = (1.f - z_)*n_ + z_*hreg[i];
      hreg[i] = hn;
      unsigned short hh = f2b(hn);
      int o = nxt*2048 + epo + i*8;
      hfH[o] = (short)hh;
      hfL[o] = (short)f2b(hn - b2f(hh));
    }
    __syncthreads();   // hf[nxt] writes visible; hf[cur] reads complete
    cur = nxt;
  }

  // -------- decoder: 12 steps; gx loop-invariant -> hoisted --------
  float w0r = w0[j], w0z = w0[128+j], w0n = w0[256+j];
  float bhr = dbhh[j], bhz = dbhh[128+j], bhn = dbhh[256+j];
  float owj = ow[j];
  float obv = ob[0];
  float gxr[4], gxz[4], gxn[4];
  #pragma unroll
  for (int i=0;i<4;++i){
    int row = g*4 + i;
    const float* gx = ctxGX + (size_t)(m0+row)*384;
    gxr[i] = gx[j]; gxz[i] = gx[128+j]; gxn[i] = gx[256+j];
  }
  for (int s = 0; s < NT; ++s){
    accf4 aR = {}, aZ = {}, aN = {};
    #pragma unroll
    for (int ks=0; ks<4; ++ks){
      GATEB(DFH, ks);
      short8 ah = *(const short8*)&hfH[cur*2048 + ks*512 + lane*8];
      short8 al = *(const short8*)&hfL[cur*2048 + ks*512 + lane*8];
      mm2(ah, al, bRh, aR);
      mm2(ah, al, bZh, aZ);
      mm2(ah, al, bNh, aN);
    }
    int nxt = cur ^ 1;
    #pragma unroll
    for (int i=0;i<4;++i){
      int row = g*4 + i;
      float p = predl[row];
      float r_ = sigf(gxr[i] + p*w0r + aR[i] + bhr);
      float z_ = sigf(gxz[i] + p*w0z + aZ[i] + bhz);
      float n_ = tanhfast(gxn[i] + p*w0n + r_*(aN[i] + bhn));
      float hn = (1.f - z_)*n_ + z_*hreg[i];
      hreg[i] = hn;
      unsigned short hh = f2b(hn);
      int o = nxt*2048 + epo + i*8;
      hfH[o] = (short)hh;
      hfL[o] = (short)f2b(hn - b2f(hh));
      float psv = hn*owj;
      psv += __shfl_xor(psv, 1, 64);
      psv += __shfl_xor(psv, 2, 64);
      psv += __shfl_xor(psv, 4, 64);
      psv += __shfl_xor(psv, 8, 64);
      if (c == 0) psl[w][row] = psv;
    }
    __syncthreads();   // psl + hf[nxt] visible
    if (tid < 16){
      float sm = obv;
      #pragma unroll
      for (int w2=0; w2<8; ++w2) sm += psl[w2][tid];
      predl[tid] = sm;
      preds_out[(size_t)s*ROWS + m0 + tid] = sm;
    }
    __syncthreads();   // predl visible for next epilogue
    cur = nxt;
  }
}

// fusion + attn gate (v2): one block per (tau, row-group); assemble frag tile
// in LDS, coalesced dword writes to global. 16 rows x 16 lanes.
__global__ __launch_bounds__(256) void k_zbuild(const float* __restrict__ x,
    const float* __restrict__ S, const float* __restrict__ cw, const float* __restrict__ cb,
    const float* __restrict__ aw, const float* __restrict__ ab,
    short* __restrict__ zfH, short* __restrict__ zfL,
    float* __restrict__ ctx, float* __restrict__ pred0){
  __shared__ float cwl[416];
  __shared__ float cbl[32];
  __shared__ float awl[65];
  __shared__ short zH[1536];
  __shared__ short zL[1536];
  int tid = threadIdx.x;
  for (int i=tid; i<416; i+=256) cwl[i] = cw[i];
  if (tid < 32) cbl[tid] = cb[tid];
  if (tid < 65) awl[tid] = aw[tid];
  {
    int* zHi = (int*)zH; int* zLi = (int*)zL;
    for (int i=tid; i<768; i+=256){ zHi[i] = 0; zLi[i] = 0; }
  }
  __syncthreads();
  int bid = blockIdx.x;             // bid = tau*RG + Rg  (matches zf layout)
  int tau = bid / RG, Rg = bid % RG;
  int trow = tid >> 4, tl = tid & 15;
  int i_ = Rg*16 + trow;
  int r = i_*NT + tau;              // scrambled reshape inverse
  int n = r % NNODE, bt = r / NNODE, t = bt % NT, b = bt / NT;
  const float* xr = x + (size_t)r*NF;
  float x0 = xr[0];
  float ce0 = cbl[tl], ce1 = cbl[tl+16];
  #pragma unroll
  for (int f=0; f<13; ++f){
    float xv = xr[1+f];
    ce0 += xv*cwl[tl*13+f];
    ce1 += xv*cwl[(tl+16)*13+f];
  }
  ce0 = fmaxf(ce0, 0.f); ce1 = fmaxf(ce1, 0.f);
  const float* sr = S + (size_t)(b*NNODE+n)*G3 + t*32;
  float sv0 = sr[tl], sv1 = sr[tl+16];
  float part = sv0*awl[1+tl] + ce0*awl[33+tl]
             + sv1*awl[17+tl] + ce1*awl[49+tl]
             + (tl==0 ? x0*awl[0] : 0.f);
  part += __shfl_xor(part, 1, 64);
  part += __shfl_xor(part, 2, 64);
  part += __shfl_xor(part, 4, 64);
  part += __shfl_xor(part, 8, 64);
  float attn = sigf(part + ab[0]);
  #define ZPUT(L, V) do{ int l_=(L); int ks_=l_>>5, q_=(l_&31)>>3, e_=l_&7; \
      int o_ = ks_*512 + ((trow + 16*q_)<<3) + e_; \
      float v_=(V); unsigned short hh_ = f2b(v_); \
      zH[o_] = (short)hh_; zL[o_] = (short)f2b(v_ - b2f(hh_)); }while(0)
  ZPUT(1+tl, sv0*attn);
  ZPUT(17+tl, sv1*attn);
  ZPUT(33+tl, ce0*attn);
  ZPUT(49+tl, ce1*attn);              // tl=15 -> l=64 (c_emb ch 31)
  if (tl == 0) ZPUT(0, x0*attn);
  #undef ZPUT
  if (t == NT-1){
    float* cr = ctx + (size_t)(b*NNODE+n)*32;
    cr[tl] = ce0; cr[tl+16] = ce1;
    if (tl == 0) pred0[b*NNODE+n] = x0;
  }
  __syncthreads();
  size_t gb = (size_t)bid*1536;
  const int* zHi = (const int*)zH; const int* zLi = (const int*)zL;
  int* gH = (int*)(zfH + gb); int* gL = (int*)(zfL + gb);
  #pragma unroll
  for (int i=tid; i<768; i+=256){ gH[i] = zHi[i]; gL[i] = zLi[i]; }
}

__global__ __launch_bounds__(256) void k_out(const float* __restrict__ preds, float* __restrict__ out){
  int idx = blockIdx.x*256 + threadIdx.x;
  if (idx >= NT*ROWS) return;
  int n = idx % NNODE;
  int t2 = idx / NNODE;
  int hor = t2 % NT;
  int b = t2 / NT;
  out[idx] = preds[(size_t)hor*ROWS + b*NNODE + n];
}

extern "C" void kernel_launch(void* const* d_in, const int* in_sizes, int n_in,
                              void* d_out, int out_size, void* d_ws, size_t ws_size,
                              hipStream_t stream){
  const float* x     = (const float*)d_in[0];
  const float* Aph   = (const float*)d_in[1];
  const float* fcw   = (const float*)d_in[2];
  const float* fcb   = (const float*)d_in[3];
  const float* alp   = (const float*)d_in[4];
  const float* cw    = (const float*)d_in[5];
  const float* cb    = (const float*)d_in[6];
  const float* tw    = (const float*)d_in[7];
  const float* tb    = (const float*)d_in[8];
  const float* theta = (const float*)d_in[9];
  const float* aw    = (const float*)d_in[10];
  const float* ab    = (const float*)d_in[11];
  const float* ewih  = (const float*)d_in[12];
  const float* ewhh  = (const float*)d_in[13];
  const float* ebih  = (const float*)d_in[14];
  const float* ebhh  = (const float*)d_in[15];
  const float* dwih  = (const float*)d_in[16];
  const float* dwhh  = (const float*)d_in[17];
  const float* dbih  = (const float*)d_in[18];
  const float* dbhh  = (const float*)d_in[19];
  const float* ow    = (const float*)d_in[20];
  const float* ob    = (const float*)d_in[21];
  float* out = (float*)d_out;

  const size_t SZ_CTX  = (size_t)ROWS*32;
  const size_t SZ_PRED = (size_t)ROWS;
  const size_t SZ_PREDS= (size_t)NT*ROWS;
  const size_t SZ_G    = (size_t)ROWS*G3;
  const size_t SZ_ABUF = (size_t)NB*NNODE*LSTR;
  const size_t SZ_EMB  = (size_t)ROWS*16;
  const size_t SZ_ZF   = (size_t)NT*RG*3*512;           // shorts per array
  const size_t SZ_UNION_FL = (2*SZ_ZF + 3) / 2;          // zfH+zfL in floats
  const size_t UNION_FL = (SZ_UNION_FL > 2*SZ_G) ? SZ_UNION_FL : 2*SZ_G;

  float* w = (float*)d_ws;
  size_t off = 0;
  auto alloc = [&](size_t nfl){ float* p = w + off; off += nfl; return p; };
  float* ctx   = alloc(SZ_CTX);
  float* pred  = alloc(SZ_PRED);
  float* preds = alloc(SZ_PREDS);
  float* Abuf  = alloc(SZ_ABUF);
  float* emb   = alloc(SZ_EMB);
  float* rsum  = alloc(SZ_PRED);
  float* lam   = alloc((size_t)NB);
  short* wS    = (short*)alloc(SH_TOTAL/2);
  float* wF    = alloc((size_t)FWT_TOTAL);
  float* Sslot = alloc(SZ_G);      // t_feat -> S -> ctxGX
  float* Uzone = alloc(UNION_FL);  // P1 | P2 during Chebyshev; zfH|zfL after
  float* P1 = Uzone;
  float* P2 = Uzone + SZ_G;
  short* zfH = (short*)Uzone;
  short* zfL = zfH + SZ_ZF;
  (void)n_in; (void)in_sizes;

  if (ws_size < off*sizeof(float)){    // tripwire: workspace too small
    k_sentinel<<<(out_size+255)/256, 256, 0, stream>>>(out, out_size);
    return;
  }

  const short* WFH = wS;
  const short* DFH = wS + 2*NW_ENC;
  float* dwihT = wF;
  float* w0    = wF + 32*384;

  k_prep<<<(PREP_TOTAL+255)/256, 256, 0, stream>>>(ewih, ewhh, dwih, dwhh, wS, wF);
  float* tfeat = Sslot;
  k_emb<<<(ROWS*16)/256, 256, 0, stream>>>(x, fcw, fcb, emb);
  k_adj<<<ROWS/4, 256, 0, stream>>>(emb, Aph, alp, Abuf, rsum);
  k_lam<<<NB, 256, 0, stream>>>(rsum, lam);
  k_lap<<<(NB*NNODE*LSTR)/256, 256, 0, stream>>>(Abuf, lam);
  k_tcn<<<(BTN*32)/256, 256, 0, stream>>>(x, tw, tb, tfeat);
  k_thetaBC<<<BTN/8, 256, 0, stream>>>(tfeat, theta, P2, P1);
  // P2 <- 2*(L @ P1) + P2
  gemm128<<<dim3(3, 2, NB), 256, 0, stream>>>(Abuf, LSTR, (long long)NNODE*LSTR,
      P1, (long long)NNODE*G3, nullptr,
      P2, (long long)NNODE*G3, 2.f, 1.f, 0,
      P2, (long long)NNODE*G3, NNODE, 13);
  k_thetaA<<<BTN/8, 256, 0, stream>>>(tfeat, theta, P1);
  // Sslot <- relu((L @ P2) + P1)
  gemm128<<<dim3(3, 2, NB), 256, 0, stream>>>(Abuf, LSTR, (long long)NNODE*LSTR,
      P2, (long long)NNODE*G3, nullptr,
      P1, (long long)NNODE*G3, 1.f, 1.f, 1,
      Sslot, (long long)NNODE*G3, NNODE, 13);
  k_zbuild<<<NT*RG, 256, 0, stream>>>(x, Sslot, cw, cb, aw, ab, zfH, zfL, ctx, pred);
  float* ctxGX = Sslot;  // S dead after zbuild
  gemm128<<<dim3(3, ROWS/128, 1), 256, 0, stream>>>(
      ctx, 32, 0, dwihT, 0, dbih,
      nullptr, 0, 1.f, 0.f, 0, ctxGX, 0, ROWS, 2);
  k_encdec<<<RG, 512, 0, stream>>>(zfH, zfL, WFH, ebih, ebhh,
      DFH, dbhh, ctxGX, w0, ow, ob, pred, preds);
  k_out<<<(NT*ROWS)/256, 256, 0, stream>>>(preds, out);
}

// Round 17
// 693.279 us; speedup vs baseline: 1.3045x; 1.0712x over previous
//
#include <hip/hip_runtime.h>
#include <math.h>

#define NB 128      // B
#define NT 12       // T
#define NNODE 207   // N
#define NF 14       // F
#define NH 128      // H
#define ROWS (NB*NNODE)      // 26496
#define BTN (NB*NT*NNODE)    // 317952
#define G3 (3*NH)            // 384
#define LSTR 208             // padded Laplacian row stride
#define RG (ROWS/16)         // 1656 row-groups of 16

typedef __attribute__((ext_vector_type(8))) short short8;   // 8 bf16 = 4 VGPR
typedef __attribute__((ext_vector_type(4))) float accf4;    // MFMA C/D

#define MFMA16 __builtin_amdgcn_mfma_f32_16x16x32_bf16

__device__ __forceinline__ float sigf(float x){ return 1.0f/(1.0f+__expf(-x)); }
__device__ __forceinline__ float tanhfast(float x){
  float e = __expf(2.f*x);
  return 1.f - 2.f/(e + 1.f);
}
__device__ __forceinline__ unsigned short f2b(float f){
  unsigned int u = __float_as_uint(f);
  return (unsigned short)((u + 0x7FFFu + ((u>>16)&1u)) >> 16);
}
__device__ __forceinline__ float b2f(unsigned short h){
  return __uint_as_float(((unsigned int)h) << 16);
}
// split-A x single-bf16-B: (ah+al) * bh  (weights RNE bf16; h/z keep split)
__device__ __forceinline__ void mm2(short8 ah, short8 al, short8 bh, accf4& acc){
  acc = MFMA16(ah, bh, acc, 0,0,0);
  acc = MFMA16(al, bh, acc, 0,0,0);
}

__global__ __launch_bounds__(256) void k_sentinel(float* __restrict__ out, int n){
  int i = blockIdx.x*256 + threadIdx.x;
  if (i < n) out[i] = 12345.0f;
}

// ---- weight prep (fragment-layout bf16 hi; lo arrays retained but unused) ----
#define NW_ENC (7*24*64*8)   // 86016
#define NW_DEC (4*24*64*8)   // 49152
#define SH_TOTAL (2*NW_ENC + 2*NW_DEC)
#define FWT_TOTAL (32*384 + 384)
#define PREP_TOTAL (NW_ENC + NW_DEC + 32*384 + 384)
__global__ __launch_bounds__(256) void k_prep(const float* __restrict__ ewih,
    const float* __restrict__ ewhh, const float* __restrict__ dwih,
    const float* __restrict__ dwhh, short* __restrict__ ws, float* __restrict__ wf){
  int i = blockIdx.x*256 + threadIdx.x;
  if (i < NW_ENC){
    int e = i & 7, lane = (i>>3) & 63, ct = (i>>9) % 24, ks = i / 12288;
    int k = ks*32 + (lane>>4)*8 + e;
    int col = ct*16 + (lane&15);
    float wv = (k < 65) ? ewih[col*65 + k] : ((k < 96) ? 0.f : ewhh[col*128 + (k-96)]);
    unsigned short hi = f2b(wv);
    ws[i] = (short)hi;
    ws[NW_ENC + i] = (short)f2b(wv - b2f(hi));
  } else if (i < NW_ENC + NW_DEC){
    int j = i - NW_ENC;
    int e = j & 7, lane = (j>>3) & 63, ct = (j>>9) % 24, ks = j / 12288;
    int k = ks*32 + (lane>>4)*8 + e;
    int col = ct*16 + (lane&15);
    float wv = dwhh[col*128 + k];
    unsigned short hi = f2b(wv);
    ws[2*NW_ENC + j] = (short)hi;
    ws[2*NW_ENC + NW_DEC + j] = (short)f2b(wv - b2f(hi));
  } else if (i < NW_ENC + NW_DEC + 32*384){
    int j = i - (NW_ENC + NW_DEC); int k = j/384, n = j%384;
    wf[j] = dwih[n*33 + 1 + k];
  } else if (i < PREP_TOTAL){
    int n = i - (NW_ENC + NW_DEC + 32*384);
    wf[32*384 + n] = dwih[n*33];
  }
}

// emb = tanh(state * fc_w + fc_b)
__global__ __launch_bounds__(256) void k_emb(const float* __restrict__ x,
    const float* __restrict__ w, const float* __restrict__ b, float* __restrict__ emb){
  int idx = blockIdx.x*256 + threadIdx.x;
  if (idx >= ROWS*16) return;
  int j = idx & 15, row = idx >> 4;
  int bb = row / NNODE, n = row % NNODE;
  float s = x[((bb*NT + (NT-1))*NNODE + n)*NF];
  emb[idx] = tanhf(s*w[j] + b[j]);
}

// wave-per-row adjacency
__global__ __launch_bounds__(256) void k_adj(const float* __restrict__ emb,
    const float* __restrict__ Aph, const float* __restrict__ alp,
    float* __restrict__ Abuf, float* __restrict__ rsum){
  int wid = threadIdx.x >> 6, lane = threadIdx.x & 63;
  int row = blockIdx.x*4 + wid;
  int bb = row / NNODE, n = row % NNODE;
  const float4* er = (const float4*)(emb + (size_t)row*16);
  float4 e0 = er[0], e1 = er[1], e2 = er[2], e3 = er[3];
  float d[4];
  #pragma unroll
  for (int q=0;q<4;++q){
    int m = lane + q*64;
    float dd = -1.f;
    if (m < NNODE){
      const float4* em = (const float4*)(emb + (size_t)(bb*NNODE+m)*16);
      float4 m0 = em[0], m1 = em[1], m2 = em[2], m3 = em[3];
      dd = e0.x*m0.x + e0.y*m0.y + e0.z*m0.z + e0.w*m0.w
         + e1.x*m1.x + e1.y*m1.y + e1.z*m1.z + e1.w*m1.w
         + e2.x*m2.x + e2.y*m2.y + e2.z*m2.z + e2.w*m2.w
         + e3.x*m3.x + e3.y*m3.y + e3.z*m3.z + e3.w*m3.w;
      dd = dd > 0.f ? dd : 0.f;
    }
    d[q] = dd;
  }
  int km = 0;
  float vmax = 0.f;
  for (int it=0; it<10; ++it){
    float v = -1.f; int mi = 1<<20;
    #pragma unroll
    for (int q=0;q<4;++q){
      if (d[q] >= 0.f && !((km>>q)&1) && d[q] > v){ v = d[q]; mi = lane + q*64; }
    }
    #pragma unroll
    for (int off=1; off<64; off<<=1){
      float v2 = __shfl_xor(v, off, 64);
      int  i2 = __shfl_xor(mi, off, 64);
      if (v2 > v || (v2 == v && i2 < mi)){ v = v2; mi = i2; }
    }
    if (it == 0) vmax = v;
    if ((mi & 63) == lane) km |= 1 << (mi >> 6);
  }
  float a = sigf(alp[0]);
  float eneg = __expf(-vmax);
  float p[4]; float ps = 0.f;
  #pragma unroll
  for (int q=0;q<4;++q){
    p[q] = 0.f;
    if (d[q] >= 0.f) p[q] = ((km>>q)&1) ? __expf(d[q]-vmax) : eneg;
    ps += p[q];
  }
  #pragma unroll
  for (int off=1; off<64; off<<=1) ps += __shfl_xor(ps, off, 64);
  float inv = (1.f - a)/ps;
  float rs = 0.f;
  #pragma unroll
  for (int q=0;q<4;++q){
    int m = lane + q*64;
    if (m < NNODE){
      float Av = a*Aph[n*NNODE + m] + p[q]*inv;
      Abuf[(size_t)row*LSTR + m] = Av;
      rs += Av;
    }
  }
  if (lane == 0) Abuf[(size_t)row*LSTR + 207] = 0.f;
  #pragma unroll
  for (int off=1; off<64; off<<=1) rs += __shfl_xor(rs, off, 64);
  if (lane == 0) rsum[row] = rs;
}

__global__ __launch_bounds__(256) void k_lam(const float* __restrict__ rsum, float* __restrict__ lam){
  __shared__ float rv[256];
  int b = blockIdx.x, tid = threadIdx.x;
  rv[tid] = (tid < NNODE) ? rsum[b*NNODE+tid] : -1e30f;
  __syncthreads();
  for (int s=128;s>0;s>>=1){ if (tid<s) rv[tid]=fmaxf(rv[tid],rv[tid+s]); __syncthreads(); }
  if (tid==0) lam[b] = fmaxf(rv[0], 1.0f);
}

__global__ __launch_bounds__(256) void k_lap(float* __restrict__ Abuf, const float* __restrict__ lam){
  int idx = blockIdx.x*256 + threadIdx.x;
  if (idx >= NB*NNODE*LSTR) return;
  int b = idx / (NNODE*LSTR);
  int rem = idx % (NNODE*LSTR);
  int n = rem / LSTR, m = rem % LSTR;
  Abuf[idx] = 2.f*Abuf[idx]/lam[b] - (n==m ? 1.f : 0.f);
}

// fused causal conv(3)+GLU+theta: PA=tf@(th0-th2), PB=tf@th1, PC=tf@th2
// layout (B, N, T*32); 8 rows per 256-thread block
__global__ __launch_bounds__(256) void k_tcntheta(const float* __restrict__ x,
    const float* __restrict__ tw, const float* __restrict__ tb,
    const float* __restrict__ theta,
    float* __restrict__ PA, float* __restrict__ PB, float* __restrict__ PC){
  __shared__ float thA[32][33], thB[32][33], thC[32][33];
  __shared__ float tf[8][32];
  int tid = threadIdx.x;
  for (int i=tid; i<1024; i+=256){
    int f = i >> 5, o = i & 31;
    float t0 = theta[f*32+o], t1 = theta[1024+f*32+o], t2 = theta[2048+f*32+o];
    thA[o][f] = t0 - t2; thB[o][f] = t1; thC[o][f] = t2;
  }
  int rl = tid >> 5, o = tid & 31;
  int r = blockIdx.x*8 + rl;
  int n = r % NNODE, bt = r / NNODE, t = bt % NT, b = bt / NT;
  float x0 = (t>=2)? x[((size_t)(b*NT+t-2)*NNODE+n)*NF] : 0.f;
  float x1 = (t>=1)? x[((size_t)(b*NT+t-1)*NNODE+n)*NF] : 0.f;
  float x2 = x[((size_t)(b*NT+t)*NNODE+n)*NF];
  float P = tb[o]    + tw[o*3]*x0       + tw[o*3+1]*x1       + tw[o*3+2]*x2;
  float Q = tb[o+32] + tw[(o+32)*3]*x0  + tw[(o+32)*3+1]*x1  + tw[(o+32)*3+2]*x2;
  tf[rl][o] = P * sigf(Q);
  __syncthreads();
  float aA=0.f, aB=0.f, aC=0.f;
  #pragma unroll
  for (int f=0; f<32; ++f){
    float tv = tf[rl][f];
    aA += tv*thA[o][f]; aB += tv*thB[o][f]; aC += tv*thC[o][f];
  }
  size_t outi = (size_t)(b*NNODE+n)*G3 + t*32 + o;
  PA[outi]=aA; PB[outi]=aB; PC[outi]=aC;
}

// ---- fp32 128x128 GEMM (Chebyshev + ctxGX) ----
__global__ __launch_bounds__(256) void gemm128(
    const float* __restrict__ Ab, int lda, long long sA,
    const float* __restrict__ Bb, long long sB,
    const float* __restrict__ bias,
    const float* __restrict__ Yb, long long sY, float alphaV, float betaV, int do_relu,
    float* __restrict__ Cb, long long sC, int M, int kchunks){
  __shared__ float As[16][132];
  __shared__ float Bs[16][132];
  int bz = blockIdx.z;
  const float* A = Ab + (size_t)bz*sA;
  const float* B = Bb + (size_t)bz*sB;
  float* C = Cb + (size_t)bz*sC;
  int n0 = blockIdx.x*128, m0 = blockIdx.y*128;
  int tid = threadIdx.x, tx = tid & 15, ty = tid >> 4;
  float acc[8][8] = {};
  int ar = tid & 127, ak = (tid >> 7)*8;
  int bk = tid >> 4, bn = (tid & 15)*8;
  for (int kc=0; kc<kchunks; ++kc){
    int k0 = kc*16;
    int m = m0 + ar;
    if (m < M){
      const float* ap = A + (size_t)m*lda + k0 + ak;
      float4 v0 = *(const float4*)ap, v1 = *(const float4*)(ap+4);
      As[ak+0][ar]=v0.x; As[ak+1][ar]=v0.y; As[ak+2][ar]=v0.z; As[ak+3][ar]=v0.w;
      As[ak+4][ar]=v1.x; As[ak+5][ar]=v1.y; As[ak+6][ar]=v1.z; As[ak+7][ar]=v1.w;
    } else {
      #pragma unroll
      for (int j=0;j<8;++j) As[ak+j][ar]=0.f;
    }
    const float* bp = B + (size_t)(k0+bk)*384 + n0 + bn;
    float4 w0_ = *(const float4*)bp, w1_ = *(const float4*)(bp+4);
    *(float4*)&Bs[bk][bn] = w0_; *(float4*)&Bs[bk][bn+4] = w1_;
    __syncthreads();
    #pragma unroll
    for (int kk=0;kk<16;++kk){
      float4 a0 = *(const float4*)&As[kk][ty*8];
      float4 a1 = *(const float4*)&As[kk][ty*8+4];
      float4 b0 = *(const float4*)&Bs[kk][tx*4];
      float4 b1 = *(const float4*)&Bs[kk][64+tx*4];
      float av[8] = {a0.x,a0.y,a0.z,a0.w,a1.x,a1.y,a1.z,a1.w};
      float bv[8] = {b0.x,b0.y,b0.z,b0.w,b1.x,b1.y,b1.z,b1.w};
      #pragma unroll
      for (int i=0;i<8;++i)
        #pragma unroll
        for (int j=0;j<8;++j) acc[i][j] += av[i]*bv[j];
    }
    __syncthreads();
  }
  if (bias){
    float bl[4], bh_[4];
    #pragma unroll
    for (int j=0;j<4;++j){ bl[j]=bias[n0+tx*4+j]; bh_[j]=bias[n0+64+tx*4+j]; }
    #pragma unroll
    for (int i=0;i<8;++i){
      int m2 = m0 + ty*8 + i; if (m2 >= M) continue;
      float4 s0, s1;
      s0.x=acc[i][0]+bl[0]; s0.y=acc[i][1]+bl[1]; s0.z=acc[i][2]+bl[2]; s0.w=acc[i][3]+bl[3];
      s1.x=acc[i][4]+bh_[0]; s1.y=acc[i][5]+bh_[1]; s1.z=acc[i][6]+bh_[2]; s1.w=acc[i][7]+bh_[3];
      *(float4*)&C[(size_t)m2*384 + n0 + tx*4] = s0;
      *(float4*)&C[(size_t)m2*384 + n0 + 64 + tx*4] = s1;
    }
  } else {
    const float* Y = Yb + (size_t)bz*sY;
    #pragma unroll
    for (int i=0;i<8;++i){
      int m2 = m0 + ty*8 + i; if (m2 >= M) continue;
      const float* yr = Y + (size_t)m2*384;
      float* cr = C + (size_t)m2*384;
      float4 y0 = *(const float4*)(yr + n0 + tx*4);
      float4 y1 = *(const float4*)(yr + n0 + 64 + tx*4);
      float4 s0, s1;
      s0.x = alphaV*acc[i][0] + betaV*y0.x; s0.y = alphaV*acc[i][1] + betaV*y0.y;
      s0.z = alphaV*acc[i][2] + betaV*y0.z; s0.w = alphaV*acc[i][3] + betaV*y0.w;
      s1.x = alphaV*acc[i][4] + betaV*y1.x; s1.y = alphaV*acc[i][5] + betaV*y1.y;
      s1.z = alphaV*acc[i][6] + betaV*y1.z; s1.w = alphaV*acc[i][7] + betaV*y1.w;
      if (do_relu){
        s0.x=fmaxf(s0.x,0.f); s0.y=fmaxf(s0.y,0.f); s0.z=fmaxf(s0.z,0.f); s0.w=fmaxf(s0.w,0.f);
        s1.x=fmaxf(s1.x,0.f); s1.y=fmaxf(s1.y,0.f); s1.z=fmaxf(s1.z,0.f); s1.w=fmaxf(s1.w,0.f);
      }
      *(float4*)(cr + n0 + tx*4) = s0;
      *(float4*)(cr + n0 + 64 + tx*4) = s1;
    }
  }
}

// ===================== persistent MFMA encoder+decoder (v7b) =====================
// 16 rows/block (grid 1656), 512 threads (8 waves). Wave w owns h-cols [16w,16w+16).
// mm2 weights; double-buffered hf (1 barrier/enc step); decoder writes out directly.
#define GATEB(WH, KS) \
    const int ko = (KS)*24; \
    short8 bRh = *(const short8*)(WH + ((size_t)(ko + w)*64 + lane)*8); \
    short8 bZh = *(const short8*)(WH + ((size_t)(ko + 8 + w)*64 + lane)*8); \
    short8 bNh = *(const short8*)(WH + ((size_t)(ko + 16 + w)*64 + lane)*8);

__global__ __launch_bounds__(512) void k_encdec(
    const short* __restrict__ zfH, const short* __restrict__ zfL,
    const short* __restrict__ WFH,
    const float* __restrict__ bih, const float* __restrict__ bhh,
    const short* __restrict__ DFH,
    const float* __restrict__ dbhh, const float* __restrict__ ctxGX,
    const float* __restrict__ w0, const float* __restrict__ ow,
    const float* __restrict__ ob, const float* __restrict__ pred0,
    float* __restrict__ outp){
  __shared__ __attribute__((aligned(16))) short hfH[2*4*512];   // [buf][ks][lane*8+e]
  __shared__ __attribute__((aligned(16))) short hfL[2*4*512];
  __shared__ float psl[8][16];
  __shared__ float predl[16];
  int R = blockIdx.x, m0 = R*16;
  int tid = threadIdx.x;
  int w = tid >> 6, lane = tid & 63;
  int g = lane >> 4, c = lane & 15;
  int j = (w<<4) + c;
  float hreg[4] = {};
  for (int i = tid; i < 4096; i += 512){ hfH[i] = 0; hfL[i] = 0; }
  if (tid < 16) predl[tid] = pred0[m0 + tid];
  // epilogue write coords: h element (row, j) -> frag (ks_h, lane', e)
  int ksh = w >> 1, qh = 2*(w&1) + (c>>3), eh = c & 7;
  int epo = ksh*512 + ((g*4) + 16*qh)*8 + eh;   // + i*8 per row
  float birv = bih[j], bizv = bih[128+j], binv = bih[256+j];
  float bhrv = bhh[j], bhzv = bhh[128+j], bhnv = bhh[256+j];
  // direct out index for tid<16
  size_t outbase = 0;
  if (tid < 16){
    int row = m0 + tid;
    int b_ = row / NNODE, n_ = row % NNODE;
    outbase = (size_t)b_*NT*NNODE + n_;
  }
  __syncthreads();

  int cur = 0;
  // -------- encoder: 12 steps, 1 barrier each (hf double-buffered) --------
  for (int t = 0; t < NT; ++t){
    accf4 aR = {}, aZ = {}, aNZ = {}, aNH = {};
    #pragma unroll
    for (int ks=0; ks<3; ++ks){
      GATEB(WFH, ks);
      size_t zb = (((size_t)t*RG + R)*3 + ks)*512;
      short8 ah = *(const short8*)(zfH + zb + lane*8);
      short8 al = *(const short8*)(zfL + zb + lane*8);
      mm2(ah, al, bRh, aR);
      mm2(ah, al, bZh, aZ);
      mm2(ah, al, bNh, aNZ);
    }
    #pragma unroll
    for (int ks=3; ks<7; ++ks){
      GATEB(WFH, ks);
      short8 ah = *(const short8*)&hfH[cur*2048 + (ks-3)*512 + lane*8];
      short8 al = *(const short8*)&hfL[cur*2048 + (ks-3)*512 + lane*8];
      mm2(ah, al, bRh, aR);
      mm2(ah, al, bZh, aZ);
      mm2(ah, al, bNh, aNH);
    }
    int nxt = cur ^ 1;
    #pragma unroll
    for (int i=0;i<4;++i){
      float r_ = sigf(aR[i] + birv + bhrv);
      float z_ = sigf(aZ[i] + bizv + bhzv);
      float n_ = tanhfast(aNZ[i] + binv + r_*(aNH[i] + bhnv));
      float hn = (1.f - z_)*n_ + z_*hreg[i];
      hreg[i] = hn;
      unsigned short hh = f2b(hn);
      int o = nxt*2048 + epo + i*8;
      hfH[o] = (short)hh;
      hfL[o] = (short)f2b(hn - b2f(hh));
    }
    __syncthreads();   // hf[nxt] writes visible; hf[cur] reads complete
    cur = nxt;
  }

  // -------- decoder: 12 steps; gx loop-invariant -> hoisted; direct out --------
  float w0r = w0[j], w0z = w0[128+j], w0n = w0[256+j];
  float bhr = dbhh[j], bhz = dbhh[128+j], bhn = dbhh[256+j];
  float owj = ow[j];
  float obv = ob[0];
  float gxr[4], gxz[4], gxn[4];
  #pragma unroll
  for (int i=0;i<4;++i){
    int row = g*4 + i;
    const float* gx = ctxGX + (size_t)(m0+row)*384;
    gxr[i] = gx[j]; gxz[i] = gx[128+j]; gxn[i] = gx[256+j];
  }
  for (int s = 0; s < NT; ++s){
    accf4 aR = {}, aZ = {}, aN = {};
    #pragma unroll
    for (int ks=0; ks<4; ++ks){
      GATEB(DFH, ks);
      short8 ah = *(const short8*)&hfH[cur*2048 + ks*512 + lane*8];
      short8 al = *(const short8*)&hfL[cur*2048 + ks*512 + lane*8];
      mm2(ah, al, bRh, aR);
      mm2(ah, al, bZh, aZ);
      mm2(ah, al, bNh, aN);
    }
    int nxt = cur ^ 1;
    #pragma unroll
    for (int i=0;i<4;++i){
      int row = g*4 + i;
      float p = predl[row];
      float r_ = sigf(gxr[i] + p*w0r + aR[i] + bhr);
      float z_ = sigf(gxz[i] + p*w0z + aZ[i] + bhz);
      float n_ = tanhfast(gxn[i] + p*w0n + r_*(aN[i] + bhn));
      float hn = (1.f - z_)*n_ + z_*hreg[i];
      hreg[i] = hn;
      unsigned short hh = f2b(hn);
      int o = nxt*2048 + epo + i*8;
      hfH[o] = (short)hh;
      hfL[o] = (short)f2b(hn - b2f(hh));
      float psv = hn*owj;
      psv += __shfl_xor(psv, 1, 64);
      psv += __shfl_xor(psv, 2, 64);
      psv += __shfl_xor(psv, 4, 64);
      psv += __shfl_xor(psv, 8, 64);
      if (c == 0) psl[w][row] = psv;
    }
    __syncthreads();   // psl + hf[nxt] visible
    if (tid < 16){
      float sm = obv;
      #pragma unroll
      for (int w2=0; w2<8; ++w2) sm += psl[w2][tid];
      predl[tid] = sm;
      outp[outbase + (size_t)s*NNODE] = sm;
    }
    __syncthreads();   // predl visible for next epilogue
    cur = nxt;
  }
}

// fusion + attn gate (v2): one block per (tau, row-group); assemble frag tile
// in LDS, coalesced dword writes to global. 16 rows x 16 lanes.
__global__ __launch_bounds__(256) void k_zbuild(const float* __restrict__ x,
    const float* __restrict__ S, const float* __restrict__ cw, const float* __restrict__ cb,
    const float* __restrict__ aw, const float* __restrict__ ab,
    short* __restrict__ zfH, short* __restrict__ zfL,
    float* __restrict__ ctx, float* __restrict__ pred0){
  __shared__ float cwl[416];
  __shared__ float cbl[32];
  __shared__ float awl[65];
  __shared__ short zH[1536];
  __shared__ short zL[1536];
  int tid = threadIdx.x;
  for (int i=tid; i<416; i+=256) cwl[i] = cw[i];
  if (tid < 32) cbl[tid] = cb[tid];
  if (tid < 65) awl[tid] = aw[tid];
  {
    int* zHi = (int*)zH; int* zLi = (int*)zL;
    for (int i=tid; i<768; i+=256){ zHi[i] = 0; zLi[i] = 0; }
  }
  __syncthreads();
  int bid = blockIdx.x;             // bid = tau*RG + Rg  (matches zf layout)
  int tau = bid / RG, Rg = bid % RG;
  int trow = tid >> 4, tl = tid & 15;
  int i_ = Rg*16 + trow;
  int r = i_*NT + tau;              // scrambled reshape inverse
  int n = r % NNODE, bt = r / NNODE, t = bt % NT, b = bt / NT;
  const float* xr = x + (size_t)r*NF;
  float x0 = xr[0];
  float ce0 = cbl[tl], ce1 = cbl[tl+16];
  #pragma unroll
  for (int f=0; f<13; ++f){
    float xv = xr[1+f];
    ce0 += xv*cwl[tl*13+f];
    ce1 += xv*cwl[(tl+16)*13+f];
  }
  ce0 = fmaxf(ce0, 0.f); ce1 = fmaxf(ce1, 0.f);
  const float* sr = S + (size_t)(b*NNODE+n)*G3 + t*32;
  float sv0 = sr[tl], sv1 = sr[tl+16];
  float part = sv0*awl[1+tl] + ce0*awl[33+tl]
             + sv1*awl[17+tl] + ce1*awl[49+tl]
             + (tl==0 ? x0*awl[0] : 0.f);
  part += __shfl_xor(part, 1, 64);
  part += __shfl_xor(part, 2, 64);
  part += __shfl_xor(part, 4, 64);
  part += __shfl_xor(part, 8, 64);
  float attn = sigf(part + ab[0]);
  #define ZPUT(L, V) do{ int l_=(L); int ks_=l_>>5, q_=(l_&31)>>3, e_=l_&7; \
      int o_ = ks_*512 + ((trow + 16*q_)<<3) + e_; \
      float v_=(V); unsigned short hh_ = f2b(v_); \
      zH[o_] = (short)hh_; zL[o_] = (short)f2b(v_ - b2f(hh_)); }while(0)
  ZPUT(1+tl, sv0*attn);
  ZPUT(17+tl, sv1*attn);
  ZPUT(33+tl, ce0*attn);
  ZPUT(49+tl, ce1*attn);              // tl=15 -> l=64 (c_emb ch 31)
  if (tl == 0) ZPUT(0, x0*attn);
  #undef ZPUT
  if (t == NT-1){
    float* cr = ctx + (size_t)(b*NNODE+n)*32;
    cr[tl] = ce0; cr[tl+16] = ce1;
    if (tl == 0) pred0[b*NNODE+n] = x0;
  }
  __syncthreads();
  size_t gb = (size_t)bid*1536;
  const int* zHi = (const int*)zH; const int* zLi = (const int*)zL;
  int* gH = (int*)(zfH + gb); int* gL = (int*)(zfL + gb);
  #pragma unroll
  for (int i=tid; i<768; i+=256){ gH[i] = zHi[i]; gL[i] = zLi[i]; }
}

extern "C" void kernel_launch(void* const* d_in, const int* in_sizes, int n_in,
                              void* d_out, int out_size, void* d_ws, size_t ws_size,
                              hipStream_t stream){
  const float* x     = (const float*)d_in[0];
  const float* Aph   = (const float*)d_in[1];
  const float* fcw   = (const float*)d_in[2];
  const float* fcb   = (const float*)d_in[3];
  const float* alp   = (const float*)d_in[4];
  const float* cw    = (const float*)d_in[5];
  const float* cb    = (const float*)d_in[6];
  const float* tw    = (const float*)d_in[7];
  const float* tb    = (const float*)d_in[8];
  const float* theta = (const float*)d_in[9];
  const float* aw    = (const float*)d_in[10];
  const float* ab    = (const float*)d_in[11];
  const float* ewih  = (const float*)d_in[12];
  const float* ewhh  = (const float*)d_in[13];
  const float* ebih  = (const float*)d_in[14];
  const float* ebhh  = (const float*)d_in[15];
  const float* dwih  = (const float*)d_in[16];
  const float* dwhh  = (const float*)d_in[17];
  const float* dbih  = (const float*)d_in[18];
  const float* dbhh  = (const float*)d_in[19];
  const float* ow    = (const float*)d_in[20];
  const float* ob    = (const float*)d_in[21];
  float* out = (float*)d_out;

  const size_t SZ_CTX  = (size_t)ROWS*32;
  const size_t SZ_PRED = (size_t)ROWS;
  const size_t SZ_G    = (size_t)ROWS*G3;
  const size_t SZ_ABUF = (size_t)NB*NNODE*LSTR;
  const size_t SZ_EMB  = (size_t)ROWS*16;
  const size_t SZ_ZF   = (size_t)NT*RG*3*512;           // shorts per array
  const size_t SZ_UNION_FL = (2*SZ_ZF + 1) / 2;          // zfH+zfL in floats
  const size_t UNION_FL = (SZ_UNION_FL > 3*SZ_G) ? SZ_UNION_FL : 3*SZ_G;

  float* w = (float*)d_ws;
  size_t off = 0;
  auto alloc = [&](size_t nfl){ float* p = w + off; off += nfl; return p; };
  float* ctx   = alloc(SZ_CTX);
  float* pred  = alloc(SZ_PRED);
  float* Abuf  = alloc(SZ_ABUF);
  float* emb   = alloc(SZ_EMB);
  float* rsum  = alloc(SZ_PRED);
  float* lam   = alloc((size_t)NB);
  short* wS    = (short*)alloc(SH_TOTAL/2);
  float* wF    = alloc((size_t)FWT_TOTAL);
  float* Sslot = alloc(SZ_G);      // S -> ctxGX
  float* Uzone = alloc(UNION_FL);  // P1|P2|P3 during Chebyshev; zfH|zfL after
  float* P1 = Uzone;
  float* P2 = Uzone + SZ_G;
  float* P3 = Uzone + 2*SZ_G;
  short* zfH = (short*)Uzone;
  short* zfL = zfH + SZ_ZF;
  (void)n_in; (void)in_sizes;

  if (ws_size < off*sizeof(float)){    // tripwire: workspace too small
    k_sentinel<<<(out_size+255)/256, 256, 0, stream>>>(out, out_size);
    return;
  }

  const short* WFH = wS;
  const short* DFH = wS + 2*NW_ENC;
  float* dwihT = wF;
  float* w0    = wF + 32*384;

  k_prep<<<(PREP_TOTAL+255)/256, 256, 0, stream>>>(ewih, ewhh, dwih, dwhh, wS, wF);
  k_emb<<<(ROWS*16)/256, 256, 0, stream>>>(x, fcw, fcb, emb);
  k_adj<<<ROWS/4, 256, 0, stream>>>(emb, Aph, alp, Abuf, rsum);
  k_lam<<<NB, 256, 0, stream>>>(rsum, lam);
  k_lap<<<(NB*NNODE*LSTR)/256, 256, 0, stream>>>(Abuf, lam);
  // fused tcn+theta: P1=RA, P2=RB, P3=RC
  k_tcntheta<<<BTN/8, 256, 0, stream>>>(x, tw, tb, theta, P1, P2, P3);
  // P2 <- 2*(L @ P3) + P2
  gemm128<<<dim3(3, 2, NB), 256, 0, stream>>>(Abuf, LSTR, (long long)NNODE*LSTR,
      P3, (long long)NNODE*G3, nullptr,
      P2, (long long)NNODE*G3, 2.f, 1.f, 0,
      P2, (long long)NNODE*G3, NNODE, 13);
  // Sslot <- relu((L @ P2) + P1)
  gemm128<<<dim3(3, 2, NB), 256, 0, stream>>>(Abuf, LSTR, (long long)NNODE*LSTR,
      P2, (long long)NNODE*G3, nullptr,
      P1, (long long)NNODE*G3, 1.f, 1.f, 1,
      Sslot, (long long)NNODE*G3, NNODE, 13);
  k_zbuild<<<NT*RG, 256, 0, stream>>>(x, Sslot, cw, cb, aw, ab, zfH, zfL, ctx, pred);
  float* ctxGX = Sslot;  // S dead after zbuild
  gemm128<<<dim3(3, ROWS/128, 1), 256, 0, stream>>>(
      ctx, 32, 0, dwihT, 0, dbih,
      nullptr, 0, 1.f, 0.f, 0, ctxGX, 0, ROWS, 2);
  k_encdec<<<RG, 512, 0, stream>>>(zfH, zfL, WFH, ebih, ebhh,
      DFH, dbhh, ctxGX, w0, ow, ob, pred, out);
}

// Round 18
// 684.003 us; speedup vs baseline: 1.3222x; 1.0136x over previous
//
#include <hip/hip_runtime.h>
#include <math.h>

#define NB 128      // B
#define NT 12       // T
#define NNODE 207   // N
#define NF 14       // F
#define NH 128      // H
#define ROWS (NB*NNODE)      // 26496
#define BTN (NB*NT*NNODE)    // 317952
#define G3 (3*NH)            // 384
#define LSTR 208             // padded adjacency row stride
#define RG (ROWS/16)         // 1656 row-groups of 16

typedef __attribute__((ext_vector_type(8))) short short8;   // 8 bf16 = 4 VGPR
typedef __attribute__((ext_vector_type(4))) float accf4;    // MFMA C/D

#define MFMA16 __builtin_amdgcn_mfma_f32_16x16x32_bf16

__device__ __forceinline__ float sigf(float x){ return 1.0f/(1.0f+__expf(-x)); }
__device__ __forceinline__ float tanhfast(float x){
  float e = __expf(2.f*x);
  return 1.f - 2.f/(e + 1.f);
}
__device__ __forceinline__ unsigned short f2b(float f){
  unsigned int u = __float_as_uint(f);
  return (unsigned short)((u + 0x7FFFu + ((u>>16)&1u)) >> 16);
}
__device__ __forceinline__ float b2f(unsigned short h){
  return __uint_as_float(((unsigned int)h) << 16);
}
// split-A x single-bf16-B (encdec): (ah+al)*bh
__device__ __forceinline__ void mm2(short8 ah, short8 al, short8 bh, accf4& acc){
  acc = MFMA16(ah, bh, acc, 0,0,0);
  acc = MFMA16(al, bh, acc, 0,0,0);
}
// split x split 3-term (cheb): ah*bh + al*bh + ah*bl  (al*bl ~2^-18, negligible)
__device__ __forceinline__ void mm3(short8 ah, short8 al, short8 bh, short8 bl, accf4& acc){
  acc = MFMA16(ah, bh, acc, 0,0,0);
  acc = MFMA16(al, bh, acc, 0,0,0);
  acc = MFMA16(ah, bl, acc, 0,0,0);
}

__global__ __launch_bounds__(256) void k_sentinel(float* __restrict__ out, int n){
  int i = blockIdx.x*256 + threadIdx.x;
  if (i < n) out[i] = 12345.0f;
}

// ---- sizes ----
#define NW_ENC (6*24*64*8)   // 73728 (z ks0-1: ewih k0..63; h ks2-5: ewhh)
#define NW_DEC (4*24*64*8)   // 49152
#define SH_TOTAL (2*NW_ENC + 2*NW_DEC)
#define FWT_TOTAL (32*384 + 384 + 384)       // dwihT | w0 | w64
#define PREP_TOTAL (NW_ENC + NW_DEC + 32*384 + 384 + 384)
#define SZ_XF (NB*7*24*512)   // 11,010,048 shorts per array
#define SZ_LF (NB*13*7*512)   //  5,963,776 shorts per array
#define SZ_ZF1 ((size_t)NT*RG*2*512)  // 20,348,928 shorts per array

__global__ __launch_bounds__(256) void k_prep(const float* __restrict__ ewih,
    const float* __restrict__ ewhh, const float* __restrict__ dwih,
    const float* __restrict__ dwhh, short* __restrict__ ws, float* __restrict__ wf){
  int i = blockIdx.x*256 + threadIdx.x;
  if (i < NW_ENC){
    int e = i & 7, lane = (i>>3) & 63, ct = (i>>9) % 24, ks = i / 12288;
    int k = ks*32 + (lane>>4)*8 + e;
    int col = ct*16 + (lane&15);
    float wv = (k < 64) ? ewih[col*65 + k] : ewhh[col*128 + (k-64)];
    unsigned short hi = f2b(wv);
    ws[i] = (short)hi;
    ws[NW_ENC + i] = (short)f2b(wv - b2f(hi));
  } else if (i < NW_ENC + NW_DEC){
    int j = i - NW_ENC;
    int e = j & 7, lane = (j>>3) & 63, ct = (j>>9) % 24, ks = j / 12288;
    int k = ks*32 + (lane>>4)*8 + e;
    int col = ct*16 + (lane&15);
    float wv = dwhh[col*128 + k];
    unsigned short hi = f2b(wv);
    ws[2*NW_ENC + j] = (short)hi;
    ws[2*NW_ENC + NW_DEC + j] = (short)f2b(wv - b2f(hi));
  } else if (i < NW_ENC + NW_DEC + 32*384){
    int j = i - (NW_ENC + NW_DEC); int k = j/384, n = j%384;
    wf[j] = dwih[n*33 + 1 + k];
  } else if (i < NW_ENC + NW_DEC + 32*384 + 384){
    int n = i - (NW_ENC + NW_DEC + 32*384);
    wf[32*384 + n] = dwih[n*33];
  } else if (i < PREP_TOTAL){
    int n = i - (NW_ENC + NW_DEC + 32*384 + 384);
    wf[32*384 + 384 + n] = ewih[n*65 + 64];   // w64
  }
}

// emb = tanh(state * fc_w + fc_b)
__global__ __launch_bounds__(256) void k_emb(const float* __restrict__ x,
    const float* __restrict__ w, const float* __restrict__ b, float* __restrict__ emb){
  int idx = blockIdx.x*256 + threadIdx.x;
  if (idx >= ROWS*16) return;
  int j = idx & 15, row = idx >> 4;
  int bb = row / NNODE, n = row % NNODE;
  float s = x[((bb*NT + (NT-1))*NNODE + n)*NF];
  emb[idx] = tanhf(s*w[j] + b[j]);
}

// wave-per-row adjacency (writes raw blended A, rowsum)
__global__ __launch_bounds__(256) void k_adj(const float* __restrict__ emb,
    const float* __restrict__ Aph, const float* __restrict__ alp,
    float* __restrict__ Abuf, float* __restrict__ rsum){
  int wid = threadIdx.x >> 6, lane = threadIdx.x & 63;
  int row = blockIdx.x*4 + wid;
  int bb = row / NNODE, n = row % NNODE;
  const float4* er = (const float4*)(emb + (size_t)row*16);
  float4 e0 = er[0], e1 = er[1], e2 = er[2], e3 = er[3];
  float d[4];
  #pragma unroll
  for (int q=0;q<4;++q){
    int m = lane + q*64;
    float dd = -1.f;
    if (m < NNODE){
      const float4* em = (const float4*)(emb + (size_t)(bb*NNODE+m)*16);
      float4 m0 = em[0], m1 = em[1], m2 = em[2], m3 = em[3];
      dd = e0.x*m0.x + e0.y*m0.y + e0.z*m0.z + e0.w*m0.w
         + e1.x*m1.x + e1.y*m1.y + e1.z*m1.z + e1.w*m1.w
         + e2.x*m2.x + e2.y*m2.y + e2.z*m2.z + e2.w*m2.w
         + e3.x*m3.x + e3.y*m3.y + e3.z*m3.z + e3.w*m3.w;
      dd = dd > 0.f ? dd : 0.f;
    }
    d[q] = dd;
  }
  int km = 0;
  float vmax = 0.f;
  for (int it=0; it<10; ++it){
    float v = -1.f; int mi = 1<<20;
    #pragma unroll
    for (int q=0;q<4;++q){
      if (d[q] >= 0.f && !((km>>q)&1) && d[q] > v){ v = d[q]; mi = lane + q*64; }
    }
    #pragma unroll
    for (int off=1; off<64; off<<=1){
      float v2 = __shfl_xor(v, off, 64);
      int  i2 = __shfl_xor(mi, off, 64);
      if (v2 > v || (v2 == v && i2 < mi)){ v = v2; mi = i2; }
    }
    if (it == 0) vmax = v;
    if ((mi & 63) == lane) km |= 1 << (mi >> 6);
  }
  float a = sigf(alp[0]);
  float eneg = __expf(-vmax);
  float p[4]; float ps = 0.f;
  #pragma unroll
  for (int q=0;q<4;++q){
    p[q] = 0.f;
    if (d[q] >= 0.f) p[q] = ((km>>q)&1) ? __expf(d[q]-vmax) : eneg;
    ps += p[q];
  }
  #pragma unroll
  for (int off=1; off<64; off<<=1) ps += __shfl_xor(ps, off, 64);
  float inv = (1.f - a)/ps;
  float rs = 0.f;
  #pragma unroll
  for (int q=0;q<4;++q){
    int m = lane + q*64;
    if (m < NNODE){
      float Av = a*Aph[n*NNODE + m] + p[q]*inv;
      Abuf[(size_t)row*LSTR + m] = Av;
      rs += Av;
    }
  }
  if (lane == 0) Abuf[(size_t)row*LSTR + 207] = 0.f;
  #pragma unroll
  for (int off=1; off<64; off<<=1) rs += __shfl_xor(rs, off, 64);
  if (lane == 0) rsum[row] = rs;
}

__global__ __launch_bounds__(256) void k_lam(const float* __restrict__ rsum, float* __restrict__ lam){
  __shared__ float rv[256];
  int b = blockIdx.x, tid = threadIdx.x;
  rv[tid] = (tid < NNODE) ? rsum[b*NNODE+tid] : -1e30f;
  __syncthreads();
  for (int s=128;s>0;s>>=1){ if (tid<s) rv[tid]=fmaxf(rv[tid],rv[tid+s]); __syncthreads(); }
  if (tid==0) lam[b] = fmaxf(rv[0], 1.0f);
}

// L = 2A/lam - I -> split-bf16 A-frag layout [b][mt13][ks7][512]
__global__ __launch_bounds__(256) void k_lapfrag(const float* __restrict__ Abuf,
    const float* __restrict__ lam, short* __restrict__ LfH, short* __restrict__ LfL){
  __shared__ short pH[7*512];
  __shared__ short pL[7*512];
  int bid = blockIdx.x;
  int b = bid / 13, mt = bid % 13;
  int tid = threadIdx.x;
  int row = tid >> 4, kq = tid & 15;
  int n = mt*16 + row;
  float invl = 2.f / lam[b];
  size_t arow = ((size_t)b*NNODE + n)*LSTR;
  #pragma unroll
  for (int kc = 0; kc < 14; ++kc){
    int k = kc*16 + kq;
    float L = 0.f;
    if (n < 207 && k < 207)
      L = Abuf[arow + k]*invl - ((n==k) ? 1.f : 0.f);
    unsigned short hh = f2b(L);
    int o = (k>>5)*512 + (row + 16*((k&31)>>3))*8 + (k&7);
    pH[o] = (short)hh;
    pL[o] = (short)f2b(L - b2f(hh));
  }
  __syncthreads();
  const int* sH = (const int*)pH; const int* sL = (const int*)pL;
  int* gH = (int*)LfH; int* gL = (int*)LfL;
  size_t basei = (size_t)bid*1792;
  for (int i = tid; i < 1792; i += 256){ gH[basei+i] = sH[i]; gL[basei+i] = sL[i]; }
}

// fused causal conv(3)+GLU+theta: P1=tf@(th0-th2), P2=tf@th1, RC=tf@th2
__global__ __launch_bounds__(256) void k_tcntheta(const float* __restrict__ x,
    const float* __restrict__ tw, const float* __restrict__ tb,
    const float* __restrict__ theta,
    float* __restrict__ PA, float* __restrict__ PB, float* __restrict__ PC){
  __shared__ float thA[32][33], thB[32][33], thC[32][33];
  __shared__ float tf[8][32];
  int tid = threadIdx.x;
  for (int i=tid; i<1024; i+=256){
    int f = i >> 5, o = i & 31;
    float t0 = theta[f*32+o], t1 = theta[1024+f*32+o], t2 = theta[2048+f*32+o];
    thA[o][f] = t0 - t2; thB[o][f] = t1; thC[o][f] = t2;
  }
  int rl = tid >> 5, o = tid & 31;
  int r = blockIdx.x*8 + rl;
  int n = r % NNODE, bt = r / NNODE, t = bt % NT, b = bt / NT;
  float x0 = (t>=2)? x[((size_t)(b*NT+t-2)*NNODE+n)*NF] : 0.f;
  float x1 = (t>=1)? x[((size_t)(b*NT+t-1)*NNODE+n)*NF] : 0.f;
  float x2 = x[((size_t)(b*NT+t)*NNODE+n)*NF];
  float P = tb[o]    + tw[o*3]*x0       + tw[o*3+1]*x1       + tw[o*3+2]*x2;
  float Q = tb[o+32] + tw[(o+32)*3]*x0  + tw[(o+32)*3+1]*x1  + tw[(o+32)*3+2]*x2;
  tf[rl][o] = P * sigf(Q);
  __syncthreads();
  float aA=0.f, aB=0.f, aC=0.f;
  #pragma unroll
  for (int f=0; f<32; ++f){
    float tv = tf[rl][f];
    aA += tv*thA[o][f]; aB += tv*thB[o][f]; aC += tv*thC[o][f];
  }
  size_t outi = (size_t)(b*NNODE+n)*G3 + t*32 + o;
  PA[outi]=aA; PB[outi]=aB; PC[outi]=aC;
}

// RC fp32 -> split B-frag layout [b][ks7][ct24][512]
__global__ __launch_bounds__(256) void k_split(const float* __restrict__ RC,
    short* __restrict__ XH, short* __restrict__ XL){
  __shared__ short pH[24*512];
  __shared__ short pL[24*512];
  int bid = blockIdx.x;            // b*7 + ks
  int b = bid / 7, ks = bid % 7;
  int tid = threadIdx.x;
  #pragma unroll
  for (int it = 0; it < 48; ++it){
    int flat = it*256 + tid;       // 0..12287
    int ml = flat / 384, col = flat % 384;
    int m = ks*32 + ml;
    float v = (m < 207) ? RC[((size_t)b*NNODE + m)*384 + col] : 0.f;
    unsigned short hh = f2b(v);
    int o = (col>>4)*512 + ((col&15) + 16*(ml>>3))*8 + (ml&7);
    pH[o] = (short)hh;
    pL[o] = (short)f2b(v - b2f(hh));
  }
  __syncthreads();
  const int* sH = (const int*)pH; const int* sL = (const int*)pL;
  int* gH = (int*)XH; int* gL = (int*)XL;
  size_t basei = (size_t)bid*6144;
  for (int i = tid; i < 6144; i += 256){ gH[basei+i] = sH[i]; gL[basei+i] = sL[i]; }
}

// ---- MFMA Chebyshev GEMM: C = L @ X (+epilogues). grid b*13, 512 thr ----
// VAR=1: out = 2*acc + Y(P2), emit split B-frags (XfB). VAR=2: S=relu(acc+Y(P1)) fp32 in-place.
template<int VAR>
__global__ __launch_bounds__(512) void gemm_cheb(
    const short* __restrict__ LfH, const short* __restrict__ LfL,
    const short* __restrict__ XH, const short* __restrict__ XL,
    const float* __restrict__ Y, float* __restrict__ Sout,
    short* __restrict__ OH, short* __restrict__ OL){
  __shared__ short pH[24*256];
  __shared__ short pL[24*256];
  int bid = blockIdx.x;
  int b = bid / 13, mt = bid % 13;
  int tid = threadIdx.x;
  int w = tid >> 6, lane = tid & 63;
  int c = lane & 15, g = lane >> 4;
  accf4 acc[3] = {};
  #pragma unroll
  for (int ks = 0; ks < 7; ++ks){
    size_t ab = ((size_t)(b*13 + mt)*7 + ks)*512 + lane*8;
    short8 ah = *(const short8*)(LfH + ab);
    short8 al = *(const short8*)(LfL + ab);
    #pragma unroll
    for (int p = 0; p < 3; ++p){
      int ct = w + p*8;
      size_t xb = ((size_t)(b*7 + ks)*24 + ct)*512 + lane*8;
      short8 bh = *(const short8*)(XH + xb);
      short8 bl = *(const short8*)(XL + xb);
      mm3(ah, al, bh, bl, acc[p]);
    }
  }
  if (VAR == 2){
    #pragma unroll
    for (int p=0;p<3;++p){
      int col = (w + p*8)*16 + c;
      #pragma unroll
      for (int i=0;i<4;++i){
        int row = mt*16 + g*4 + i;
        if (row < 207){
          size_t idx = ((size_t)b*NNODE + row)*384 + col;
          float v = acc[p][i] + Y[idx];
          Sout[idx] = fmaxf(v, 0.f);
        }
      }
    }
  } else {
    #pragma unroll
    for (int p=0;p<3;++p){
      int ct = w + p*8;
      int col = ct*16 + c;
      #pragma unroll
      for (int i=0;i<4;++i){
        int r16 = g*4 + i;
        int row = mt*16 + r16;
        float v = 0.f;
        if (row < 207) v = 2.f*acc[p][i] + Y[((size_t)b*NNODE + row)*384 + col];
        unsigned short hh = f2b(v);
        int o = ct*256 + (c + 16*(r16>>3))*8 + (r16 & 7);
        pH[o] = (short)hh;
        pL[o] = (short)f2b(v - b2f(hh));
      }
    }
    __syncthreads();
    int ksn = mt >> 1, half = mt & 1;
    const int* sH = (const int*)pH; const int* sL = (const int*)pL;
    int* gH = (int*)OH; int* gL = (int*)OL;
    for (int i = tid; i < 3072; i += 512){
      int ct = i >> 7, idx = i & 127;
      size_t gi = ((size_t)(b*7 + ksn)*24 + ct)*256 + (size_t)half*128 + idx;
      gH[gi] = sH[i]; gL[gi] = sL[i];
    }
    if (mt == 12){
      for (int i = tid; i < 3072; i += 512){
        int ct = i >> 7, idx = i & 127;
        size_t gi = ((size_t)(b*7 + 6)*24 + ct)*256 + 128 + idx;
        gH[gi] = 0; gL[gi] = 0;
      }
    }
  }
}

// ---- fp32 128x128 GEMM (ctxGX only) ----
__global__ __launch_bounds__(256) void gemm128(
    const float* __restrict__ Ab, int lda, long long sA,
    const float* __restrict__ Bb, long long sB,
    const float* __restrict__ bias,
    const float* __restrict__ Yb, long long sY, float alphaV, float betaV, int do_relu,
    float* __restrict__ Cb, long long sC, int M, int kchunks){
  __shared__ float As[16][132];
  __shared__ float Bs[16][132];
  int bz = blockIdx.z;
  const float* A = Ab + (size_t)bz*sA;
  const float* B = Bb + (size_t)bz*sB;
  float* C = Cb + (size_t)bz*sC;
  int n0 = blockIdx.x*128, m0 = blockIdx.y*128;
  int tid = threadIdx.x, tx = tid & 15, ty = tid >> 4;
  float acc[8][8] = {};
  int ar = tid & 127, ak = (tid >> 7)*8;
  int bk = tid >> 4, bn = (tid & 15)*8;
  for (int kc=0; kc<kchunks; ++kc){
    int k0 = kc*16;
    int m = m0 + ar;
    if (m < M){
      const float* ap = A + (size_t)m*lda + k0 + ak;
      float4 v0 = *(const float4*)ap, v1 = *(const float4*)(ap+4);
      As[ak+0][ar]=v0.x; As[ak+1][ar]=v0.y; As[ak+2][ar]=v0.z; As[ak+3][ar]=v0.w;
      As[ak+4][ar]=v1.x; As[ak+5][ar]=v1.y; As[ak+6][ar]=v1.z; As[ak+7][ar]=v1.w;
    } else {
      #pragma unroll
      for (int j=0;j<8;++j) As[ak+j][ar]=0.f;
    }
    const float* bp = B + (size_t)(k0+bk)*384 + n0 + bn;
    float4 w0_ = *(const float4*)bp, w1_ = *(const float4*)(bp+4);
    *(float4*)&Bs[bk][bn] = w0_; *(float4*)&Bs[bk][bn+4] = w1_;
    __syncthreads();
    #pragma unroll
    for (int kk=0;kk<16;++kk){
      float4 a0 = *(const float4*)&As[kk][ty*8];
      float4 a1 = *(const float4*)&As[kk][ty*8+4];
      float4 b0 = *(const float4*)&Bs[kk][tx*4];
      float4 b1 = *(const float4*)&Bs[kk][64+tx*4];
      float av[8] = {a0.x,a0.y,a0.z,a0.w,a1.x,a1.y,a1.z,a1.w};
      float bv[8] = {b0.x,b0.y,b0.z,b0.w,b1.x,b1.y,b1.z,b1.w};
      #pragma unroll
      for (int i=0;i<8;++i)
        #pragma unroll
        for (int j=0;j<8;++j) acc[i][j] += av[i]*bv[j];
    }
    __syncthreads();
  }
  if (bias){
    float bl[4], bh_[4];
    #pragma unroll
    for (int j=0;j<4;++j){ bl[j]=bias[n0+tx*4+j]; bh_[j]=bias[n0+64+tx*4+j]; }
    #pragma unroll
    for (int i=0;i<8;++i){
      int m2 = m0 + ty*8 + i; if (m2 >= M) continue;
      float4 s0, s1;
      s0.x=acc[i][0]+bl[0]; s0.y=acc[i][1]+bl[1]; s0.z=acc[i][2]+bl[2]; s0.w=acc[i][3]+bl[3];
      s1.x=acc[i][4]+bh_[0]; s1.y=acc[i][5]+bh_[1]; s1.z=acc[i][6]+bh_[2]; s1.w=acc[i][7]+bh_[3];
      *(float4*)&C[(size_t)m2*384 + n0 + tx*4] = s0;
      *(float4*)&C[(size_t)m2*384 + n0 + 64 + tx*4] = s1;
    }
  }
}

// ===================== persistent MFMA encoder+decoder (v8) =====================
// z: 2 frag-ksteps + exact fp32 z64 rank-1 term; h split in LDS dbuf; mm2 weights.
#define GATEB(WH, KS) \
    const int ko = (KS)*24; \
    short8 bRh = *(const short8*)(WH + ((size_t)(ko + w)*64 + lane)*8); \
    short8 bZh = *(const short8*)(WH + ((size_t)(ko + 8 + w)*64 + lane)*8); \
    short8 bNh = *(const short8*)(WH + ((size_t)(ko + 16 + w)*64 + lane)*8);

__global__ __launch_bounds__(512) void k_encdec(
    const short* __restrict__ zfH, const short* __restrict__ zfL,
    const float* __restrict__ z64, const short* __restrict__ WFH,
    const float* __restrict__ bih, const float* __restrict__ bhh,
    const short* __restrict__ DFH,
    const float* __restrict__ dbhh, const float* __restrict__ ctxGX,
    const float* __restrict__ w0, const float* __restrict__ w64,
    const float* __restrict__ ow,
    const float* __restrict__ ob, const float* __restrict__ pred0,
    float* __restrict__ outp){
  __shared__ __attribute__((aligned(16))) short hfH[2*4*512];
  __shared__ __attribute__((aligned(16))) short hfL[2*4*512];
  __shared__ float psl[8][16];
  __shared__ float predl[16];
  int R = blockIdx.x, m0 = R*16;
  int tid = threadIdx.x;
  int w = tid >> 6, lane = tid & 63;
  int g = lane >> 4, c = lane & 15;
  int j = (w<<4) + c;
  float hreg[4] = {};
  for (int i = tid; i < 4096; i += 512){ hfH[i] = 0; hfL[i] = 0; }
  if (tid < 16) predl[tid] = pred0[m0 + tid];
  int ksh = w >> 1, qh = 2*(w&1) + (c>>3), eh = c & 7;
  int epo = ksh*512 + ((g*4) + 16*qh)*8 + eh;
  float birv = bih[j], bizv = bih[128+j], binv = bih[256+j];
  float bhrv = bhh[j], bhzv = bhh[128+j], bhnv = bhh[256+j];
  float w64r = w64[j], w64z = w64[128+j], w64n = w64[256+j];
  size_t outbase = 0;
  if (tid < 16){
    int row = m0 + tid;
    int b_ = row / NNODE, n_ = row % NNODE;
    outbase = (size_t)b_*NT*NNODE + n_;
  }
  __syncthreads();

  int cur = 0;
  // -------- encoder: 12 steps --------
  for (int t = 0; t < NT; ++t){
    accf4 aR = {}, aZ = {}, aNZ = {}, aNH = {};
    #pragma unroll
    for (int ks=0; ks<2; ++ks){
      GATEB(WFH, ks);
      size_t zb = (((size_t)t*RG + R)*2 + ks)*512;
      short8 ah = *(const short8*)(zfH + zb + lane*8);
      short8 al = *(const short8*)(zfL + zb + lane*8);
      mm2(ah, al, bRh, aR);
      mm2(ah, al, bZh, aZ);
      mm2(ah, al, bNh, aNZ);
    }
    #pragma unroll
    for (int ks=2; ks<6; ++ks){
      GATEB(WFH, ks);
      short8 ah = *(const short8*)&hfH[cur*2048 + (ks-2)*512 + lane*8];
      short8 al = *(const short8*)&hfL[cur*2048 + (ks-2)*512 + lane*8];
      mm2(ah, al, bRh, aR);
      mm2(ah, al, bZh, aZ);
      mm2(ah, al, bNh, aNH);
    }
    float z64v[4];
    #pragma unroll
    for (int i=0;i<4;++i) z64v[i] = z64[(size_t)t*ROWS + m0 + g*4 + i];
    int nxt = cur ^ 1;
    #pragma unroll
    for (int i=0;i<4;++i){
      float r_ = sigf(aR[i] + z64v[i]*w64r + birv + bhrv);
      float z_ = sigf(aZ[i] + z64v[i]*w64z + bizv + bhzv);
      float n_ = tanhfast(aNZ[i] + z64v[i]*w64n + binv + r_*(aNH[i] + bhnv));
      float hn = (1.f - z_)*n_ + z_*hreg[i];
      hreg[i] = hn;
      unsigned short hh = f2b(hn);
      int o = nxt*2048 + epo + i*8;
      hfH[o] = (short)hh;
      hfL[o] = (short)f2b(hn - b2f(hh));
    }
    __syncthreads();
    cur = nxt;
  }

  // -------- decoder: 12 steps --------
  float w0r = w0[j], w0z = w0[128+j], w0n = w0[256+j];
  float bhr = dbhh[j], bhz = dbhh[128+j], bhn = dbhh[256+j];
  float owj = ow[j];
  float obv = ob[0];
  float gxr[4], gxz[4], gxn[4];
  #pragma unroll
  for (int i=0;i<4;++i){
    int row = g*4 + i;
    const float* gx = ctxGX + (size_t)(m0+row)*384;
    gxr[i] = gx[j]; gxz[i] = gx[128+j]; gxn[i] = gx[256+j];
  }
  for (int s = 0; s < NT; ++s){
    accf4 aR = {}, aZ = {}, aN = {};
    #pragma unroll
    for (int ks=0; ks<4; ++ks){
      GATEB(DFH, ks);
      short8 ah = *(const short8*)&hfH[cur*2048 + ks*512 + lane*8];
      short8 al = *(const short8*)&hfL[cur*2048 + ks*512 + lane*8];
      mm2(ah, al, bRh, aR);
      mm2(ah, al, bZh, aZ);
      mm2(ah, al, bNh, aN);
    }
    int nxt = cur ^ 1;
    #pragma unroll
    for (int i=0;i<4;++i){
      int row = g*4 + i;
      float p = predl[row];
      float r_ = sigf(gxr[i] + p*w0r + aR[i] + bhr);
      float z_ = sigf(gxz[i] + p*w0z + aZ[i] + bhz);
      float n_ = tanhfast(gxn[i] + p*w0n + r_*(aN[i] + bhn));
      float hn = (1.f - z_)*n_ + z_*hreg[i];
      hreg[i] = hn;
      unsigned short hh = f2b(hn);
      int o = nxt*2048 + epo + i*8;
      hfH[o] = (short)hh;
      hfL[o] = (short)f2b(hn - b2f(hh));
      float psv = hn*owj;
      psv += __shfl_xor(psv, 1, 64);
      psv += __shfl_xor(psv, 2, 64);
      psv += __shfl_xor(psv, 4, 64);
      psv += __shfl_xor(psv, 8, 64);
      if (c == 0) psl[w][row] = psv;
    }
    __syncthreads();
    if (tid < 16){
      float sm = obv;
      #pragma unroll
      for (int w2=0; w2<8; ++w2) sm += psl[w2][tid];
      predl[tid] = sm;
      outp[outbase + (size_t)s*NNODE] = sm;
    }
    __syncthreads();
    cur = nxt;
  }
}

// fusion + attn gate: frag tile in LDS, coalesced out; z64 exact fp32
__global__ __launch_bounds__(256) void k_zbuild(const float* __restrict__ x,
    const float* __restrict__ S, const float* __restrict__ cw, const float* __restrict__ cb,
    const float* __restrict__ aw, const float* __restrict__ ab,
    short* __restrict__ zfH, short* __restrict__ zfL, float* __restrict__ z64,
    float* __restrict__ ctx, float* __restrict__ pred0){
  __shared__ float cwl[416];
  __shared__ float cbl[32];
  __shared__ float awl[65];
  __shared__ short zH[1024];
  __shared__ short zL[1024];
  int tid = threadIdx.x;
  for (int i=tid; i<416; i+=256) cwl[i] = cw[i];
  if (tid < 32) cbl[tid] = cb[tid];
  if (tid < 65) awl[tid] = aw[tid];
  __syncthreads();
  int bid = blockIdx.x;             // tau*RG + Rg
  int tau = bid / RG, Rg = bid % RG;
  int trow = tid >> 4, tl = tid & 15;
  int i_ = Rg*16 + trow;
  int r = i_*NT + tau;
  int n = r % NNODE, bt = r / NNODE, t = bt % NT, b = bt / NT;
  const float* xr = x + (size_t)r*NF;
  float x0 = xr[0];
  float ce0 = cbl[tl], ce1 = cbl[tl+16];
  #pragma unroll
  for (int f=0; f<13; ++f){
    float xv = xr[1+f];
    ce0 += xv*cwl[tl*13+f];
    ce1 += xv*cwl[(tl+16)*13+f];
  }
  ce0 = fmaxf(ce0, 0.f); ce1 = fmaxf(ce1, 0.f);
  const float* sr = S + (size_t)(b*NNODE+n)*G3 + t*32;
  float sv0 = sr[tl], sv1 = sr[tl+16];
  float part = sv0*awl[1+tl] + ce0*awl[33+tl]
             + sv1*awl[17+tl] + ce1*awl[49+tl]
             + (tl==0 ? x0*awl[0] : 0.f);
  part += __shfl_xor(part, 1, 64);
  part += __shfl_xor(part, 2, 64);
  part += __shfl_xor(part, 4, 64);
  part += __shfl_xor(part, 8, 64);
  float attn = sigf(part + ab[0]);
  #define ZPUT(L, V) do{ int l_=(L); int ks_=l_>>5, q_=(l_&31)>>3, e_=l_&7; \
      int o_ = ks_*512 + ((trow + 16*q_)<<3) + e_; \
      float v_=(V); unsigned short hh_ = f2b(v_); \
      zH[o_] = (short)hh_; zL[o_] = (short)f2b(v_ - b2f(hh_)); }while(0)
  ZPUT(1+tl, sv0*attn);
  ZPUT(17+tl, sv1*attn);
  ZPUT(33+tl, ce0*attn);
  if (tl < 15) ZPUT(49+tl, ce1*attn);
  else z64[(size_t)tau*ROWS + i_] = ce1*attn;   // l=64 exact fp32
  if (tl == 0) ZPUT(0, x0*attn);
  #undef ZPUT
  if (t == NT-1){
    float* cr = ctx + (size_t)(b*NNODE+n)*32;
    cr[tl] = ce0; cr[tl+16] = ce1;
    if (tl == 0) pred0[b*NNODE+n] = x0;
  }
  __syncthreads();
  size_t gb = (size_t)bid*512;       // ints per array
  const int* zHi = (const int*)zH; const int* zLi = (const int*)zL;
  int* gH = (int*)zfH; int* gL = (int*)zfL;
  #pragma unroll
  for (int i=tid; i<512; i+=256){ gH[gb+i] = zHi[i]; gL[gb+i] = zLi[i]; }
}

extern "C" void kernel_launch(void* const* d_in, const int* in_sizes, int n_in,
                              void* d_out, int out_size, void* d_ws, size_t ws_size,
                              hipStream_t stream){
  const float* x     = (const float*)d_in[0];
  const float* Aph   = (const float*)d_in[1];
  const float* fcw   = (const float*)d_in[2];
  const float* fcb   = (const float*)d_in[3];
  const float* alp   = (const float*)d_in[4];
  const float* cw    = (const float*)d_in[5];
  const float* cb    = (const float*)d_in[6];
  const float* tw    = (const float*)d_in[7];
  const float* tb    = (const float*)d_in[8];
  const float* theta = (const float*)d_in[9];
  const float* aw    = (const float*)d_in[10];
  const float* ab    = (const float*)d_in[11];
  const float* ewih  = (const float*)d_in[12];
  const float* ewhh  = (const float*)d_in[13];
  const float* ebih  = (const float*)d_in[14];
  const float* ebhh  = (const float*)d_in[15];
  const float* dwih  = (const float*)d_in[16];
  const float* dwhh  = (const float*)d_in[17];
  const float* dbih  = (const float*)d_in[18];
  const float* dbhh  = (const float*)d_in[19];
  const float* ow    = (const float*)d_in[20];
  const float* ob    = (const float*)d_in[21];
  float* out = (float*)d_out;

  const size_t SZ_G    = (size_t)ROWS*G3;           // 10,174,464
  const size_t SZ_ABUF = (size_t)NB*NNODE*LSTR;     //  5,511,168
  const size_t SZ_EMB  = (size_t)ROWS*16;
  const size_t U_FL    = 2*SZ_G + 2*(size_t)SZ_XF + (size_t)SZ_LF;  // 48,332,800

  float* wp = (float*)d_ws;
  size_t off = 0;
  auto alloc = [&](size_t nfl){ float* p = wp + off; off += nfl; return p; };
  float* pred  = alloc((size_t)ROWS);
  float* lam   = alloc((size_t)NB);
  short* wS    = (short*)alloc(SH_TOTAL/2);
  float* wF    = alloc((size_t)FWT_TOTAL);
  float* z64   = alloc((size_t)NT*ROWS);
  float* U     = alloc(U_FL);
  (void)n_in; (void)in_sizes;

  if (ws_size < off*sizeof(float)){    // tripwire: workspace too small
    k_sentinel<<<(out_size+255)/256, 256, 0, stream>>>(out, out_size);
    return;
  }

  // U overlays (phase-disjoint):
  float* Abuf  = U;                               // phase 0 (adj/lam/lapfrag)
  float* embp  = U + SZ_ABUF;                     // phase 0
  float* rsum  = U + SZ_ABUF + SZ_EMB;            // phase 0
  float* P1    = U;                               // tcntheta onward; S in-place
  float* P2    = U + SZ_G;
  short* fbase = (short*)(U + 2*SZ_G);
  short* XfAH  = fbase;
  short* XfAL  = fbase + SZ_XF;
  short* XfBH  = fbase + 2*(size_t)SZ_XF;
  short* XfBL  = fbase + 3*(size_t)SZ_XF;
  short* LfH   = fbase + 4*(size_t)SZ_XF;
  short* LfL   = LfH + SZ_LF;
  float* RCbuf = (float*)XfBH;                    // RC fp32 until k_split
  short* zfH   = (short*)(U + SZ_G);              // after cheb (over P2+XfA head)
  short* zfL   = zfH + SZ_ZF1;
  float* ctxGX = (float*)XfBH;                    // after zbuild (XfB dead)
  float* ctx   = U + 2*SZ_G + (size_t)SZ_XF*2;    // Lf float offset (Lf dead)

  const short* WFH = wS;
  const short* DFH = wS + 2*NW_ENC;
  float* dwihT = wF;
  float* w0    = wF + 32*384;
  float* w64   = wF + 32*384 + 384;

  k_prep<<<(PREP_TOTAL+255)/256, 256, 0, stream>>>(ewih, ewhh, dwih, dwhh, wS, wF);
  k_emb<<<(ROWS*16)/256, 256, 0, stream>>>(x, fcw, fcb, embp);
  k_adj<<<ROWS/4, 256, 0, stream>>>(embp, Aph, alp, Abuf, rsum);
  k_lam<<<NB, 256, 0, stream>>>(rsum, lam);
  k_lapfrag<<<NB*13, 256, 0, stream>>>(Abuf, lam, LfH, LfL);
  k_tcntheta<<<BTN/8, 256, 0, stream>>>(x, tw, tb, theta, P1, P2, RCbuf);
  k_split<<<NB*7, 256, 0, stream>>>(RCbuf, XfAH, XfAL);
  // P2' = 2*L@RC + P2 -> XfB frags
  gemm_cheb<1><<<NB*13, 512, 0, stream>>>(LfH, LfL, XfAH, XfAL, P2,
      nullptr, XfBH, XfBL);
  // S = relu(L@P2' + P1) -> in-place P1
  gemm_cheb<2><<<NB*13, 512, 0, stream>>>(LfH, LfL, XfBH, XfBL, P1,
      P1, nullptr, nullptr);
  k_zbuild<<<NT*RG, 256, 0, stream>>>(x, P1, cw, cb, aw, ab, zfH, zfL, z64,
      ctx, pred);
  gemm128<<<dim3(3, ROWS/128, 1), 256, 0, stream>>>(
      ctx, 32, 0, dwihT, 0, dbih,
      nullptr, 0, 1.f, 0.f, 0, ctxGX, 0, ROWS, 2);
  k_encdec<<<RG, 512, 0, stream>>>(zfH, zfL, z64, WFH, ebih, ebhh,
      DFH, dbhh, ctxGX, w0, w64, ow, ob, pred, out);
}